// Round 13
// baseline (273.713 us; speedup 1.0000x reference)
//
#include <hip/hip_runtime.h>
#include <hip/hip_bf16.h>

#define NBLK  50000
#define NATOM 400000
#define NEDGE 800000
#define NTILE 6250             // 64-atom tiles

typedef __bf16 bf16x8 __attribute__((ext_vector_type(8)));
typedef __bf16 bf16x4 __attribute__((ext_vector_type(4)));
typedef float  f32x4  __attribute__((ext_vector_type(4)));

// ---- workspace layout (bytes); fits proven WS_NEED = 18,403,840 ----
#define TSTART_OFF 0UL         // int32[6251]: tile edge counts -> exclusive offsets
#define TCUR_OFF   25008UL     // int32[6250]: scatter cursors
#define EW1_OFF    50048UL     // f32[100][128] = emb@W1+b1
#define REC_OFF    101248UL    // u16[800000]: (pair*64 + dst_local), grouped by tile
#define T_OFF      1701264UL   // f32[500][128]: msg table; REWRITTEN to TW1 = T@W1
#define PW_OFF     1957264UL   // bf16[1024][128]: sinusoid @ W0[0:128]
#define W2T_OFF    2219408UL   // bf16[128][128]: (rs8*W2@W0[128:256])^T [n][k]
#define M1T_OFF    2252176UL   // bf16[128][128] mlp_w1^T
#define M2T_OFF    2284944UL   // bf16[128][128] mlp_w2^T
#define AAW_OFF    2317712UL   // f32[4][128]
#define GM_OFF     2319760UL   // u8[50000]
#define FLAG_OFF   2369760UL   // int32 sniff flag
#define TOPO_OFF   2369792UL   // bf16[50000][128] topo_pre
#define WS_NEED    18403840UL

#define RS8 0.35355339059327373f

#define MFMA(a,b,c) __builtin_amdgcn_mfma_f32_16x16x32_bf16((a),(b),(c),0,0,0)

__device__ inline f32x4 splat4(float v){ f32x4 r; r[0]=v; r[1]=v; r[2]=v; r[3]=v; return r; }
__device__ inline float scrub(float v){ return (v==v && v<1e30f && v>-1e30f) ? v : 0.f; }

// ---------------- dtype sniff for generate_mask (1 block) ----------------
__global__ void k_sniff(const void* gm_raw, char* ws) {
  __shared__ int big;
  if (threadIdx.x == 0) big = 0;
  __syncthreads();
  const unsigned* gw = (const unsigned*)gm_raw;
  for (int i = threadIdx.x; i < 12500; i += 256)
    if (gw[i] > 1u) big = 1;
  __syncthreads();
  if (threadIdx.x == 0) *(int*)(ws + FLAG_OFF) = big;
}

// ---- prep (merged): T, M1T/M2T, gm canon, PW, W2T', AAW ----
// blocks: [0,100) T, [100,116) transposes, [116,166) gm, [166,1190) PW,
// [1190,1318) W2T, [1318,1322) AAW
__global__ void k_prep(const float* atom_embed, const float* bond_embed,
                       const float* m0, const float* m1, const float* m2,
                       const float* g2, const float* gb2, const float* aa_embed,
                       const void* gm_raw, char* ws) {
  int b = blockIdx.x, t = threadIdx.x;
  if (b < 100) {                       // T[a*5+bond][c] = relu(ae + be), f32
    float ae = atom_embed[b*128 + t];
    float* T = (float*)(ws + T_OFF);
    for (int bo = 0; bo < 5; ++bo) {
      float v = ae + bond_embed[bo*128 + t];
      T[(b*5 + bo)*128 + t] = v > 0.f ? v : 0.f;
    }
  } else if (b < 116) {                // weight transposes f32 -> bf16 [n][k]
    int wb = b - 100;
    const float* src; __bf16* dst; int r0;
    if (wb < 8) { src = m1; dst = (__bf16*)(ws + M1T_OFF); r0 = wb*16; }
    else        { src = m2; dst = (__bf16*)(ws + M2T_OFF); r0 = (wb-8)*16; }
    for (int rr = 0; rr < 16; ++rr) {
      int r = r0 + rr;
      dst[t*128 + r] = (__bf16)src[r*128 + t];
    }
  } else if (b < 166) {                // gm canon: 50 blocks x 1000 elems
    int anyBig = *(const int*)(ws + FLAG_OFF);
    int base = (b - 116) * 1000;
    unsigned char* gu = (unsigned char*)(ws + GM_OFF);
    if (anyBig) {
      const unsigned char* gb = (const unsigned char*)gm_raw;
      for (int i = t; i < 1000; i += 128) gu[base+i] = gb[base+i] ? 1 : 0;
    } else {
      const int* gi = (const int*)gm_raw;
      for (int i = t; i < 1000; i += 128) gu[base+i] = gi[base+i] ? 1 : 0;
    }
  } else if (b < 1190) {               // PW[p][t] = sum_j s(p,j)*W0[j][t], bf16
    int p = b - 166;
    __shared__ float s[128];
    int c = t & 63;
    float invf = exp2f((float)c * -0.20762050593046012f);  // 10000^(-c/64)
    float ang = (float)p * invf;
    s[t] = (t < 64) ? __sinf(ang) : __cosf(ang);
    __syncthreads();
    float acc = 0.f;
    #pragma unroll 4
    for (int j = 0; j < 128; ++j) acc += s[j] * m0[j*128 + t];
    ((__bf16*)(ws + PW_OFF))[p*128 + t] = (__bf16)acc;
  } else if (b < 1318) {               // W2T[c][r] = rs8 * sum_j W2[r][j]*W0[128+j][c]
    int r = b - 1190;
    float acc = 0.f;
    #pragma unroll 4
    for (int j = 0; j < 128; ++j) acc += g2[r*128 + j] * m0[(128+j)*128 + t];
    ((__bf16*)(ws + W2T_OFF))[t*128 + r] = (__bf16)(acc * RS8);
  } else {                             // AAW[sf][t], sf = sel + 2*f
    int sf = b - 1318, sel = sf & 1, f = sf >> 1;
    float acc = 0.f;
    #pragma unroll 4
    for (int j = 0; j < 128; ++j) acc += aa_embed[sel*128 + j] * m0[(256+j)*128 + t];
    if (f) {
      float cacc = 0.f;
      #pragma unroll 4
      for (int j = 0; j < 128; ++j) cacc += gb2[j] * m0[(128+j)*128 + t];
      acc += 8.0f * RS8 * cacc;
    }
    ((float*)(ws + AAW_OFF))[sf*128 + t] = acc;
  }
}

// ------- prep2: EW1 = emb@W1+b1, TW1 = T@W1 (in place over T) -------
__global__ void k_prep2(const float* atom_embed, const float* g1, const float* gb1,
                        char* ws) {
  int b = blockIdx.x, t = threadIdx.x;
  float s0 = 0.f, s1 = 0.f, s2 = 0.f, s3 = 0.f;
  const float* row = (b < 100) ? (atom_embed + b*128) : ((float*)(ws + T_OFF) + (b-100)*128);
  #pragma unroll 4
  for (int k = 0; k < 128; k += 4) {
    s0 += row[k+0] * g1[(k+0)*128 + t];
    s1 += row[k+1] * g1[(k+1)*128 + t];
    s2 += row[k+2] * g1[(k+2)*128 + t];
    s3 += row[k+3] * g1[(k+3)*128 + t];
  }
  float s = (s0 + s1) + (s2 + s3);
  if (b < 100) {
    ((float*)(ws + EW1_OFF))[b*128 + t] = s + gb1[t];
  } else {
    __syncthreads();
    ((float*)(ws + T_OFF))[(b-100)*128 + t] = s;
  }
}

// ---------------- count per TILE: 4 edges/thread ----------------
__global__ void k_count4(const int* __restrict__ bonds, char* ws) {
  int base = (blockIdx.x*256 + threadIdx.x)*4;
  if (base >= NEDGE) return;
  const unsigned char* gm = (const unsigned char*)(ws + GM_OFF);
  const int4* bp = (const int4*)(bonds + base*3);
  int4 w0 = bp[0], w1 = bp[1], w2 = bp[2];
  int srcs[4] = {w0.x, w0.w, w1.z, w2.y};
  int dsts[4] = {w0.y, w1.x, w1.w, w2.z};
  #pragma unroll
  for (int i = 0; i < 4; ++i) {
    if (gm[srcs[i] >> 3] | gm[dsts[i] >> 3]) continue;
    atomicAdd((int*)(ws + TSTART_OFF) + (dsts[i] >> 6), 1);
  }
}

// ---------------- scan 6250 tile counts: single block ----------------
__global__ void k_scan_t(char* ws) {
  __shared__ int s[1024]; __shared__ int carry;
  int t = threadIdx.x;
  int* ts = (int*)(ws + TSTART_OFF);
  int* tc = (int*)(ws + TCUR_OFF);
  if (t == 0) carry = 0;
  __syncthreads();
  for (int c = 0; c < 7; ++c) {
    int i = c*1024 + t;
    int v = (i < NTILE) ? ts[i] : 0;
    s[t] = v; __syncthreads();
    for (int d = 1; d < 1024; d <<= 1) {
      int x = (t >= d) ? s[t-d] : 0;
      __syncthreads(); s[t] += x; __syncthreads();
    }
    int excl = s[t] - v + carry;
    if (i < NTILE) { ts[i] = excl; tc[i] = excl; }
    int tot = s[1023]; __syncthreads();
    if (t == 0) carry += tot;
    __syncthreads();
  }
  if (t == 0) ts[NTILE] = carry;
}

// ---------------- scatter tile-grouped records: 4 edges/thread ----------------
__global__ void k_scatter4(const int* __restrict__ bonds, const int* __restrict__ A, char* ws) {
  int base = (blockIdx.x*256 + threadIdx.x)*4;
  if (base >= NEDGE) return;
  const unsigned char* gm = (const unsigned char*)(ws + GM_OFF);
  const int4* bp = (const int4*)(bonds + base*3);
  int4 w0 = bp[0], w1 = bp[1], w2 = bp[2];
  int srcs[4] = {w0.x, w0.w, w1.z, w2.y};
  int dsts[4] = {w0.y, w1.x, w1.w, w2.z};
  int bts[4]  = {w0.z, w1.y, w2.x, w2.w};
  #pragma unroll
  for (int i = 0; i < 4; ++i) {
    if (gm[srcs[i] >> 3] | gm[dsts[i] >> 3]) continue;
    int slot = atomicAdd((int*)(ws + TCUR_OFF) + (dsts[i] >> 6), 1);
    if (slot >= 0 && slot < NEDGE)
      ((unsigned short*)(ws + REC_OFF))[slot] =
        (unsigned short)((A[srcs[i]]*5 + bts[i])*64 + (dsts[i] & 63));
  }
}

// ---- gather: per-tile edge-parallel. LDS f32[64][128] (swizzled), LDS atomics ----
// phase A: stage EW1 rows; phase B: uniform edge sweep (8 thr/edge, ds atomics);
// phase C: relu + 8-row sum -> topo_pre bf16.
__launch_bounds__(256)
__global__ void k_gather_t(char* ws, const int* __restrict__ A) {
  __shared__ float smF[8192];            // 32 KB
  const int tid = threadIdx.x;
  const int tile = blockIdx.x;
  const int a0 = tile * 64;
  const unsigned char* gm = (const unsigned char*)(ws + GM_OFF);

  {  // phase A
    const int al = tid >> 2, q = tid & 3;
    const int atom = a0 + al;
    int masked = gm[atom >> 3];
    int aT = masked ? 0 : A[atom];
    const f32x4* ep = (const f32x4*)((const float*)(ws + EW1_OFF) + aT*128 + q*32);
    #pragma unroll
    for (int j = 0; j < 8; ++j) {
      f32x4 v = masked ? splat4(0.f) : ep[j];
      int fi = al*128 + ((q*32 + j*4) ^ ((al & 7) << 2));
      *(f32x4*)&smF[fi] = v;
    }
  }
  __syncthreads();

  {  // phase B
    const int* ts = (const int*)(ws + TSTART_OFF);
    const unsigned short* rec = (const unsigned short*)(ws + REC_OFF);
    const float* TW1 = (const float*)(ws + T_OFF);
    int e0 = ts[tile], e1 = ts[tile+1];
    if (e0 < 0) e0 = 0;
    if (e1 > NEDGE) e1 = NEDGE;
    const int g = tid >> 3, q8 = tid & 7;
    for (int e = e0 + g; e < e1; e += 32) {
      int rv = rec[e];
      int p = rv >> 6, dl = rv & 63;
      if (p >= 500) p = 0;               // defensive
      const f32x4* tp = (const f32x4*)(TW1 + p*128 + q8*16);
      #pragma unroll
      for (int j = 0; j < 4; ++j) {
        f32x4 t = tp[j];
        int fi = dl*128 + ((q8*16 + j*4) ^ ((dl & 7) << 2));
        atomicAdd(&smF[fi+0], t[0]);
        atomicAdd(&smF[fi+1], t[1]);
        atomicAdd(&smF[fi+2], t[2]);
        atomicAdd(&smF[fi+3], t[3]);
      }
    }
  }
  __syncthreads();

  {  // phase C
    const int ml = tid >> 5, cs = tid & 31;
    const int mol = tile*8 + ml;
    float s0 = 0.f, s1 = 0.f, s2 = 0.f, s3 = 0.f;
    if (!gm[mol]) {
      #pragma unroll
      for (int r = 0; r < 8; ++r) {
        int row = ml*8 + r;
        f32x4 v = *(const f32x4*)&smF[row*128 + ((cs*4) ^ ((row & 7) << 2))];
        s0 += fmaxf(v[0], 0.f); s1 += fmaxf(v[1], 0.f);
        s2 += fmaxf(v[2], 0.f); s3 += fmaxf(v[3], 0.f);
      }
    }
    bf16x4 o;
    o[0] = (__bf16)s0; o[1] = (__bf16)s1; o[2] = (__bf16)s2; o[3] = (__bf16)s3;
    *(bf16x4*)((char*)ws + TOPO_OFF + (long)mol*256 + cs*8) = o;
  }
}

// ------------- GEMM core: 64x128 tile, 4 waves, K=128, single LDS panel -------------
__device__ inline void gemm4(const char* sm, int aoff, const __bf16* wt,
                             const float* bias, int lane, int wave, f32x4 acc[4][2]) {
  const int colA = wave*32 + (lane & 15);
  const int k0   = (lane >> 4) * 8;
  float bb0 = bias[colA], bb1 = bias[colA + 16];
  #pragma unroll
  for (int m = 0; m < 4; ++m) { acc[m][0] = splat4(bb0); acc[m][1] = splat4(bb1); }
  #pragma unroll
  for (int kb = 0; kb < 4; ++kb) {
    bf16x8 b0 = *(const bf16x8*)(wt + colA*128 + kb*32 + k0);
    bf16x8 b1 = *(const bf16x8*)(wt + (colA+16)*128 + kb*32 + k0);
    #pragma unroll
    for (int m = 0; m < 4; ++m) {
      int rA = m*16 + (lane & 15);
      int byte = aoff + rA*256 + (((kb*64) + k0*2) ^ ((rA & 7) << 4));
      bf16x8 a = *(const bf16x8*)(sm + byte);
      acc[m][0] = MFMA(a, b0, acc[m][0]);
      acc[m][1] = MFMA(a, b1, acc[m][1]);
    }
  }
}

__device__ inline void stor4(char* sm, int off, f32x4 acc[4][2],
                             int lane, int wave, bool do_relu) {
  #pragma unroll
  for (int m = 0; m < 4; ++m)
  #pragma unroll
  for (int nf = 0; nf < 2; ++nf)
  #pragma unroll
  for (int r = 0; r < 4; ++r) {
    float v = acc[m][nf][r];
    if (do_relu && v < 0.f) v = 0.f;
    int row = m*16 + (lane >> 4)*4 + r;
    int col = wave*32 + nf*16 + (lane & 15);
    int byte = off + row*256 + ((col*2) ^ ((row & 7) << 4));
    *(__bf16*)(sm + byte) = (__bf16)v;
  }
}

// ---- mlp3: stage topo_pre -> GEMM_T(K=128)+epilogue(PW/AAW) -> GEMM1 -> GEMM3 ----
__launch_bounds__(256)
__global__ void k_mlp3(char* ws, const int* __restrict__ pos_ids,
                       const int* __restrict__ is_aa, const float* cr,
                       const float* mb0, const float* mb1, const float* mb2,
                       float* __restrict__ out) {
  __shared__ __align__(16) char sm[32768];
  const int tid = threadIdx.x, lane = tid & 63, wave = tid >> 6;
  const int r0 = blockIdx.x * 64;
  const unsigned char* gm = (const unsigned char*)(ws + GM_OFF);
  const __bf16* topo_pre = (const __bf16*)(ws + TOPO_OFF);

  for (int i = 0; i < 4; ++i) {          // stage topo panel @0
    int idx = tid + i*256;
    int row = idx >> 4, c = idx & 15;
    int mol = r0 + row;
    bf16x8 v;
    #pragma unroll
    for (int j = 0; j < 8; ++j) v[j] = (__bf16)0.f;
    if (mol < NBLK) v = *(const bf16x8*)(topo_pre + (long)mol*128 + c*8);
    int byte = row*256 + ((c*16) ^ ((row & 7) << 4));
    *(bf16x8*)(sm + byte) = v;
  }
  if (tid < 64) {                        // per-row scalars @16384
    int mol = r0 + tid, packed = 0;
    if (mol < NBLK) {
      int g = gm[mol];
      int corrupt = g && (cr[mol] < 0.1f);
      int sel = corrupt ? 0 : is_aa[mol];
      packed = pos_ids[mol] | (sel << 12) | ((g ? 0 : 1) << 13);
    }
    *(int*)(sm + 16384 + tid*4) = packed;
  }
  __syncthreads();

  f32x4 acc[4][2];
  gemm4(sm, 0, (const __bf16*)(ws + W2T_OFF), mb0, lane, wave, acc);
  {
    const __bf16* PW = (const __bf16*)(ws + PW_OFF);
    const float* AAW = (const float*)(ws + AAW_OFF);
    #pragma unroll
    for (int m = 0; m < 4; ++m)
    #pragma unroll
    for (int r = 0; r < 4; ++r) {
      int row = m*16 + (lane >> 4)*4 + r;
      int packed = *(const int*)(sm + 16384 + row*4);
      int pid = packed & 0xFFF, sf = (packed >> 12) & 3;
      #pragma unroll
      for (int nf = 0; nf < 2; ++nf) {
        int col = wave*32 + nf*16 + (lane & 15);
        float v = acc[m][nf][r] + (float)PW[pid*128 + col] + AAW[sf*128 + col];
        acc[m][nf][r] = fmaxf(v, 0.f);
      }
    }
  }
  __syncthreads();
  stor4(sm, 0, acc, lane, wave, false);  // h1 over topo panel
  __syncthreads();

  gemm4(sm, 0, (const __bf16*)(ws + M1T_OFF), mb1, lane, wave, acc);
  stor4(sm, 16384, acc, lane, wave, true);
  __syncthreads();

  gemm4(sm, 16384, (const __bf16*)(ws + M2T_OFF), mb2, lane, wave, acc);
  #pragma unroll
  for (int m = 0; m < 4; ++m)
  #pragma unroll
  for (int nf = 0; nf < 2; ++nf)
  #pragma unroll
  for (int r = 0; r < 4; ++r) {
    int row = m*16 + (lane >> 4)*4 + r;
    int col = wave*32 + nf*16 + (lane & 15);
    int mol = r0 + row;
    if (mol < NBLK) out[(long)mol*128 + col] = scrub(acc[m][nf][r]);
  }
}

extern "C" void kernel_launch(void* const* d_in, const int* in_sizes, int n_in,
                              void* d_out, int out_size, void* d_ws, size_t ws_size,
                              hipStream_t stream) {
  if (ws_size < WS_NEED) return;   // diagnostic: absmax-fail instead of fault
  const int* A      = (const int*)d_in[0];
  const int* bonds  = (const int*)d_in[1];
  const void* gm    = d_in[3];
  const int* pos    = (const int*)d_in[4];
  const int* isaa   = (const int*)d_in[5];
  const float* cr   = (const float*)d_in[6];
  const float* atom_embed = (const float*)d_in[7];
  const float* bond_embed = (const float*)d_in[8];
  const float* aa_embed   = (const float*)d_in[9];
  const float* g1  = (const float*)d_in[10];
  const float* gb1 = (const float*)d_in[11];
  const float* g2  = (const float*)d_in[12];
  const float* gb2 = (const float*)d_in[13];
  const float* m0  = (const float*)d_in[14];
  const float* mb0 = (const float*)d_in[15];
  const float* m1  = (const float*)d_in[16];
  const float* mb1 = (const float*)d_in[17];
  const float* m2  = (const float*)d_in[18];
  const float* mb2 = (const float*)d_in[19];
  char* ws = (char*)d_ws;

  hipMemsetAsync(ws + TSTART_OFF, 0, (size_t)(NTILE+1)*4, stream);
  k_sniff   <<<1, 256, 0, stream>>>(gm, ws);
  k_prep    <<<1322, 128, 0, stream>>>(atom_embed, bond_embed, m0, m1, m2,
                                       g2, gb2, aa_embed, gm, ws);
  k_count4  <<<782, 256, 0, stream>>>(bonds, ws);
  k_scan_t  <<<1, 1024, 0, stream>>>(ws);
  k_scatter4<<<782, 256, 0, stream>>>(bonds, A, ws);
  k_prep2   <<<600, 128, 0, stream>>>(atom_embed, g1, gb1, ws);   // EW1, TW1
  k_gather_t<<<NTILE, 256, 0, stream>>>(ws, A);
  k_mlp3    <<<(NBLK + 63)/64, 256, 0, stream>>>(ws, pos, isaa, cr,
                                                 mb0, mb1, mb2, (float*)d_out);
}

// Round 14
// 147.237 us; speedup vs baseline: 1.8590x; 1.8590x over previous
//
#include <hip/hip_runtime.h>
#include <hip/hip_bf16.h>

#define NBLK  50000
#define NATOM 400000
#define NEDGE 800000
#define NBS   1563            // ceil(400000/256)

typedef __bf16 bf16x8 __attribute__((ext_vector_type(8)));
typedef __bf16 bf16x4 __attribute__((ext_vector_type(4)));
typedef float  f32x4  __attribute__((ext_vector_type(4)));

// ---- workspace layout (bytes); fits proven WS_NEED = 18,403,840 ----
#define START_OFF 0UL          // int32[400001]: counts -> exclusive offsets
#define CUR_OFF   1600016UL    // int32[400000]: cursors; REUSED as EW1 f32[100][128]
#define BS_OFF    3200016UL    // int32[1563]
#define REC_OFF   3206288UL    // u16[800000]: per-edge pair ids, CSR by dst atom
#define T_OFF     4806288UL    // f32[500][128]: msg table; REWRITTEN to TW1 = T@W1
#define PW_OFF    5062288UL    // bf16[1024][128]: sinusoid @ W0[0:128]
#define W2T_OFF   5324432UL    // bf16[128][128]: (rs8*W2@W0[128:256])^T [n][k]
#define M1T_OFF   5357200UL    // bf16[128][128] mlp_w1^T
#define M2T_OFF   5389968UL    // bf16[128][128] mlp_w2^T
#define AAW_OFF   5422736UL    // f32[4][128]
#define GM_OFF    5424784UL    // u8[50000]
#define FLAG_OFF  5474784UL    // int32 sniff flag
#define TOPO_OFF  5474816UL    // bf16[50000][128] topo_pre
#define WS_NEED   18403840UL

#define RS8 0.35355339059327373f

#define MFMA(a,b,c) __builtin_amdgcn_mfma_f32_16x16x32_bf16((a),(b),(c),0,0,0)

__device__ inline f32x4 splat4(float v){ f32x4 r; r[0]=v; r[1]=v; r[2]=v; r[3]=v; return r; }
__device__ inline float scrub(float v){ return (v==v && v<1e30f && v>-1e30f) ? v : 0.f; }

// ---------------- dtype sniff for generate_mask (1 block) ----------------
__global__ void k_sniff(const void* gm_raw, char* ws) {
  __shared__ int big;
  if (threadIdx.x == 0) big = 0;
  __syncthreads();
  const unsigned* gw = (const unsigned*)gm_raw;
  for (int i = threadIdx.x; i < 12500; i += 256)
    if (gw[i] > 1u) big = 1;
  __syncthreads();
  if (threadIdx.x == 0) *(int*)(ws + FLAG_OFF) = big;
}

// ---- prep (merged): T, M1T/M2T, gm canon, PW, W2T', AAW, edge COUNT ----
// blocks: [0,100) T, [100,116) transposes, [116,166) gm, [166,1190) PW,
// [1190,1318) W2T, [1318,1322) AAW, [1322,2885) count (reads RAW gm via flag)
__global__ void k_prep(const float* atom_embed, const float* bond_embed,
                       const float* m0, const float* m1, const float* m2,
                       const float* g2, const float* gb2, const float* aa_embed,
                       const void* gm_raw, const int* __restrict__ bonds, char* ws) {
  int b = blockIdx.x, t = threadIdx.x;
  if (b < 100) {                       // T[a*5+bond][c] = relu(ae + be), f32
    float ae = atom_embed[b*128 + t];
    float* T = (float*)(ws + T_OFF);
    for (int bo = 0; bo < 5; ++bo) {
      float v = ae + bond_embed[bo*128 + t];
      T[(b*5 + bo)*128 + t] = v > 0.f ? v : 0.f;
    }
  } else if (b < 116) {                // weight transposes f32 -> bf16 [n][k]
    int wb = b - 100;
    const float* src; __bf16* dst; int r0;
    if (wb < 8) { src = m1; dst = (__bf16*)(ws + M1T_OFF); r0 = wb*16; }
    else        { src = m2; dst = (__bf16*)(ws + M2T_OFF); r0 = (wb-8)*16; }
    for (int rr = 0; rr < 16; ++rr) {
      int r = r0 + rr;
      dst[t*128 + r] = (__bf16)src[r*128 + t];
    }
  } else if (b < 166) {                // gm canon: 50 blocks x 1000 elems
    int anyBig = *(const int*)(ws + FLAG_OFF);
    int base = (b - 116) * 1000;
    unsigned char* gu = (unsigned char*)(ws + GM_OFF);
    if (anyBig) {
      const unsigned char* gb = (const unsigned char*)gm_raw;
      for (int i = t; i < 1000; i += 128) gu[base+i] = gb[base+i] ? 1 : 0;
    } else {
      const int* gi = (const int*)gm_raw;
      for (int i = t; i < 1000; i += 128) gu[base+i] = gi[base+i] ? 1 : 0;
    }
  } else if (b < 1190) {               // PW[p][t] = sum_j s(p,j)*W0[j][t], bf16
    int p = b - 166;
    __shared__ float s[128];
    int c = t & 63;
    float invf = exp2f((float)c * -0.20762050593046012f);  // 10000^(-c/64)
    float ang = (float)p * invf;
    s[t] = (t < 64) ? __sinf(ang) : __cosf(ang);
    __syncthreads();
    float acc = 0.f;
    #pragma unroll 4
    for (int j = 0; j < 128; ++j) acc += s[j] * m0[j*128 + t];
    ((__bf16*)(ws + PW_OFF))[p*128 + t] = (__bf16)acc;
  } else if (b < 1318) {               // W2T[c][r] = rs8 * sum_j W2[r][j]*W0[128+j][c]
    int r = b - 1190;
    float acc = 0.f;
    #pragma unroll 4
    for (int j = 0; j < 128; ++j) acc += g2[r*128 + j] * m0[(128+j)*128 + t];
    ((__bf16*)(ws + W2T_OFF))[t*128 + r] = (__bf16)(acc * RS8);
  } else if (b < 1322) {               // AAW[sf][t], sf = sel + 2*f
    int sf = b - 1318, sel = sf & 1, f = sf >> 1;
    float acc = 0.f;
    #pragma unroll 4
    for (int j = 0; j < 128; ++j) acc += aa_embed[sel*128 + j] * m0[(256+j)*128 + t];
    if (f) {
      float cacc = 0.f;
      #pragma unroll 4
      for (int j = 0; j < 128; ++j) cacc += gb2[j] * m0[(128+j)*128 + t];
      acc += 8.0f * RS8 * cacc;
    }
    ((float*)(ws + AAW_OFF))[sf*128 + t] = acc;
  } else {                             // COUNT: 4 edges/thread, raw gm reads
    int anyBig = *(const int*)(ws + FLAG_OFF);
    const unsigned char* g8 = (const unsigned char*)gm_raw;
    const int* g32 = (const int*)gm_raw;
    int base = ((b - 1322)*128 + t)*4;
    if (base < NEDGE) {
      const int4* bp = (const int4*)(bonds + (long)base*3);
      int4 w0 = bp[0], w1 = bp[1], w2 = bp[2];
      int srcs[4] = {w0.x, w0.w, w1.z, w2.y};
      int dsts[4] = {w0.y, w1.x, w1.w, w2.z};
      #pragma unroll
      for (int i = 0; i < 4; ++i) {
        int sm_ = srcs[i] >> 3, dm = dsts[i] >> 3;
        int bad = anyBig ? ((int)g8[sm_] | (int)g8[dm]) : (g32[sm_] | g32[dm]);
        if (!bad) atomicAdd((int*)(ws + START_OFF) + dsts[i], 1);
      }
    }
  }
}

// ------- prep2 (AFTER scatter): EW1 -> CUR region, TW1 = T@W1 in place -------
__global__ void k_prep2(const float* atom_embed, const float* g1, const float* gb1,
                        char* ws) {
  int b = blockIdx.x, t = threadIdx.x;
  float s0 = 0.f, s1 = 0.f, s2 = 0.f, s3 = 0.f;
  const float* row = (b < 100) ? (atom_embed + b*128) : ((float*)(ws + T_OFF) + (b-100)*128);
  #pragma unroll 4
  for (int k = 0; k < 128; k += 4) {
    s0 += row[k+0] * g1[(k+0)*128 + t];
    s1 += row[k+1] * g1[(k+1)*128 + t];
    s2 += row[k+2] * g1[(k+2)*128 + t];
    s3 += row[k+3] * g1[(k+3)*128 + t];
  }
  float s = (s0 + s1) + (s2 + s3);
  if (b < 100) {
    ((float*)(ws + CUR_OFF))[b*128 + t] = s + gb1[t];
  } else {
    __syncthreads();
    ((float*)(ws + T_OFF))[(b-100)*128 + t] = s;
  }
}

// ---------------- exclusive scan over 400000 counts ----------------
__global__ void k_scan1(char* ws) {
  __shared__ int s[256];
  int b = blockIdx.x, t = threadIdx.x, i = b*256 + t;
  int* cnt = (int*)(ws + START_OFF);
  int v = (i < NATOM) ? cnt[i] : 0;
  s[t] = v; __syncthreads();
  for (int d = 1; d < 256; d <<= 1) {
    int x = (t >= d) ? s[t-d] : 0;
    __syncthreads(); s[t] += x; __syncthreads();
  }
  if (i < NATOM) cnt[i] = s[t] - v;
  if (t == 255) ((int*)(ws + BS_OFF))[b] = s[255];
}
__global__ void k_scan2(char* ws) {
  __shared__ int s[256]; __shared__ int carry;
  int t = threadIdx.x;
  int* bs = (int*)(ws + BS_OFF);
  if (t == 0) carry = 0;
  __syncthreads();
  for (int c = 0; c < 7; ++c) {
    int i = c*256 + t;
    int v = (i < NBS) ? bs[i] : 0;
    s[t] = v; __syncthreads();
    for (int d = 1; d < 256; d <<= 1) {
      int x = (t >= d) ? s[t-d] : 0;
      __syncthreads(); s[t] += x; __syncthreads();
    }
    int excl = s[t] - v + carry;
    if (i < NBS) bs[i] = excl;
    int tot = s[255]; __syncthreads();
    if (t == 0) carry += tot;
    __syncthreads();
  }
  if (t == 0) ((int*)(ws + START_OFF))[NATOM] = carry;
}
__global__ void k_scan3(char* ws) {
  int b = blockIdx.x, i = b*256 + threadIdx.x;
  if (i >= NATOM) return;
  int* start = (int*)(ws + START_OFF);
  int v = start[i] + ((int*)(ws + BS_OFF))[b];
  start[i] = v;
  ((int*)(ws + CUR_OFF))[i] = v;
}

// ---------------- scatter: 4 edges/thread (canon gm) ----------------
__global__ void k_scatter4(const int* __restrict__ bonds, const int* __restrict__ A, char* ws) {
  int base = (blockIdx.x*256 + threadIdx.x)*4;
  if (base >= NEDGE) return;
  const unsigned char* gm = (const unsigned char*)(ws + GM_OFF);
  const int4* bp = (const int4*)(bonds + (long)base*3);
  int4 w0 = bp[0], w1 = bp[1], w2 = bp[2];
  int srcs[4] = {w0.x, w0.w, w1.z, w2.y};
  int dsts[4] = {w0.y, w1.x, w1.w, w2.z};
  int bts[4]  = {w0.z, w1.y, w2.x, w2.w};
  #pragma unroll
  for (int i = 0; i < 4; ++i) {
    if (gm[srcs[i] >> 3] | gm[dsts[i] >> 3]) continue;
    int slot = atomicAdd((int*)(ws + CUR_OFF) + dsts[i], 1);
    if (slot >= 0 && slot < NEDGE)
      ((unsigned short*)(ws + REC_OFF))[slot] = (unsigned short)(A[srcs[i]]*5 + bts[i]);
  }
}

// ---- gather2: 128 atoms/block, 2 atoms/thread (ILP x2 on the CSR latency chain) ----
// phase 1: u[32]/v[32] = relu(EW1[A] + sum TW1[rec]) -> bf16 LDS [128][128] swizzled
// phase 2: 16 mols: sum 8 rows -> topo_pre
__launch_bounds__(256)
__global__ void k_gather2(char* ws, const int* __restrict__ A) {
  __shared__ __align__(16) char sm[32768];
  const int tid = threadIdx.x;
  const int row0 = blockIdx.x * 128;                // atom base
  const unsigned char* gm = (const unsigned char*)(ws + GM_OFF);
  const int* start = (const int*)(ws + START_OFF);
  const unsigned short* rec = (const unsigned short*)(ws + REC_OFF);
  const float* EW1 = (const float*)(ws + CUR_OFF);
  const float* TW1 = (const float*)(ws + T_OFF);

  {
    const int rowL = tid >> 2, q = tid & 3;
    const int atomA = row0 + rowL, atomB = atomA + 64;
    // hoisted independent loads: two chains in flight
    int mA = gm[atomA >> 3], mB = gm[atomB >> 3];
    int aTA = A[atomA], aTB = A[atomB];
    int s0A = start[atomA], s1A = start[atomA+1];
    int s0B = start[atomB], s1B = start[atomB+1];
    float u[32], v[32];
    #pragma unroll
    for (int k = 0; k < 32; ++k) { u[k] = 0.f; v[k] = 0.f; }
    if (!mA) {
      const f32x4* ep = (const f32x4*)(EW1 + aTA*128 + q*32);
      #pragma unroll
      for (int j = 0; j < 8; ++j) {
        f32x4 tv = ep[j];
        #pragma unroll
        for (int k = 0; k < 4; ++k) u[j*4+k] = tv[k];
      }
    } else { s0A = 0; s1A = 0; }
    if (!mB) {
      const f32x4* ep = (const f32x4*)(EW1 + aTB*128 + q*32);
      #pragma unroll
      for (int j = 0; j < 8; ++j) {
        f32x4 tv = ep[j];
        #pragma unroll
        for (int k = 0; k < 4; ++k) v[j*4+k] = tv[k];
      }
    } else { s0B = 0; s1B = 0; }
    if (s0A < 0) s0A = 0;
    if (s1A > NEDGE) s1A = NEDGE;
    if (s0B < 0) s0B = 0;
    if (s1B > NEDGE) s1B = NEDGE;
    // merged interleaved walk: two independent rec->TW1 chains per iteration
    int sA = s0A, sB = s0B;
    while (sA < s1A || sB < s1B) {
      if (sA < s1A) {
        int p = rec[sA];
        if (p >= 500) p = 0;
        const f32x4* tp = (const f32x4*)(TW1 + p*128 + q*32);
        #pragma unroll
        for (int j = 0; j < 8; ++j) {
          f32x4 tv = tp[j];
          #pragma unroll
          for (int k = 0; k < 4; ++k) u[j*4+k] += tv[k];
        }
        ++sA;
      }
      if (sB < s1B) {
        int p = rec[sB];
        if (p >= 500) p = 0;
        const f32x4* tp = (const f32x4*)(TW1 + p*128 + q*32);
        #pragma unroll
        for (int j = 0; j < 8; ++j) {
          f32x4 tv = tp[j];
          #pragma unroll
          for (int k = 0; k < 4; ++k) v[j*4+k] += tv[k];
        }
        ++sB;
      }
    }
    #pragma unroll
    for (int j = 0; j < 4; ++j) {
      bf16x8 oU, oV;
      #pragma unroll
      for (int k = 0; k < 8; ++k) {
        oU[k] = (__bf16)fmaxf(u[j*8+k], 0.f);
        oV[k] = (__bf16)fmaxf(v[j*8+k], 0.f);
      }
      int cb = (q*64) + j*16;
      int rA = rowL, rB = rowL + 64;
      *(bf16x8*)(sm + rA*256 + (cb ^ ((rA & 7) << 4))) = oU;
      *(bf16x8*)(sm + rB*256 + (cb ^ ((rB & 7) << 4))) = oV;
    }
  }
  __syncthreads();

  {  // phase 2: 16 mols x 32 col-chunks = 512 assignments, 2 per thread
    #pragma unroll
    for (int h = 0; h < 2; ++h) {
      int idx = tid + h*256;
      int ml = idx >> 5, cs = idx & 31;
      int mol = blockIdx.x*16 + ml;
      float s0 = 0.f, s1 = 0.f, s2 = 0.f, s3 = 0.f;
      #pragma unroll
      for (int r = 0; r < 8; ++r) {
        int row = ml*8 + r;
        int byte = row*256 + ((cs*8) ^ ((row & 7) << 4));
        bf16x4 vv = *(const bf16x4*)(sm + byte);
        s0 += (float)vv[0]; s1 += (float)vv[1]; s2 += (float)vv[2]; s3 += (float)vv[3];
      }
      bf16x4 o;
      o[0] = (__bf16)s0; o[1] = (__bf16)s1; o[2] = (__bf16)s2; o[3] = (__bf16)s3;
      *(bf16x4*)((char*)ws + TOPO_OFF + (long)mol*256 + cs*8) = o;
    }
  }
}

// ------------- GEMM core: 64x128 tile, 4 waves, K=128, single LDS panel -------------
__device__ inline void gemm4(const char* sm, int aoff, const __bf16* wt,
                             const float* bias, int lane, int wave, f32x4 acc[4][2]) {
  const int colA = wave*32 + (lane & 15);
  const int k0   = (lane >> 4) * 8;
  float bb0 = bias[colA], bb1 = bias[colA + 16];
  #pragma unroll
  for (int m = 0; m < 4; ++m) { acc[m][0] = splat4(bb0); acc[m][1] = splat4(bb1); }
  #pragma unroll
  for (int kb = 0; kb < 4; ++kb) {
    bf16x8 b0 = *(const bf16x8*)(wt + colA*128 + kb*32 + k0);
    bf16x8 b1 = *(const bf16x8*)(wt + (colA+16)*128 + kb*32 + k0);
    #pragma unroll
    for (int m = 0; m < 4; ++m) {
      int rA = m*16 + (lane & 15);
      int byte = aoff + rA*256 + (((kb*64) + k0*2) ^ ((rA & 7) << 4));
      bf16x8 a = *(const bf16x8*)(sm + byte);
      acc[m][0] = MFMA(a, b0, acc[m][0]);
      acc[m][1] = MFMA(a, b1, acc[m][1]);
    }
  }
}

__device__ inline void stor4(char* sm, int off, f32x4 acc[4][2],
                             int lane, int wave, bool do_relu) {
  #pragma unroll
  for (int m = 0; m < 4; ++m)
  #pragma unroll
  for (int nf = 0; nf < 2; ++nf)
  #pragma unroll
  for (int r = 0; r < 4; ++r) {
    float v = acc[m][nf][r];
    if (do_relu && v < 0.f) v = 0.f;
    int row = m*16 + (lane >> 4)*4 + r;
    int col = wave*32 + nf*16 + (lane & 15);
    int byte = off + row*256 + ((col*2) ^ ((row & 7) << 4));
    *(__bf16*)(sm + byte) = (__bf16)v;
  }
}

// ---- mlp3: stage topo_pre -> GEMM_T(K=128)+epilogue(PW/AAW) -> GEMM1 -> GEMM3 ----
__launch_bounds__(256)
__global__ void k_mlp3(char* ws, const int* __restrict__ pos_ids,
                       const int* __restrict__ is_aa, const float* cr,
                       const float* mb0, const float* mb1, const float* mb2,
                       float* __restrict__ out) {
  __shared__ __align__(16) char sm[32768];
  const int tid = threadIdx.x, lane = tid & 63, wave = tid >> 6;
  const int r0 = blockIdx.x * 64;
  const unsigned char* gm = (const unsigned char*)(ws + GM_OFF);
  const __bf16* topo_pre = (const __bf16*)(ws + TOPO_OFF);

  for (int i = 0; i < 4; ++i) {          // stage topo panel @0
    int idx = tid + i*256;
    int row = idx >> 4, c = idx & 15;
    int mol = r0 + row;
    bf16x8 v;
    #pragma unroll
    for (int j = 0; j < 8; ++j) v[j] = (__bf16)0.f;
    if (mol < NBLK) v = *(const bf16x8*)(topo_pre + (long)mol*128 + c*8);
    int byte = row*256 + ((c*16) ^ ((row & 7) << 4));
    *(bf16x8*)(sm + byte) = v;
  }
  if (tid < 64) {                        // per-row scalars @16384
    int mol = r0 + tid, packed = 0;
    if (mol < NBLK) {
      int g = gm[mol];
      int corrupt = g && (cr[mol] < 0.1f);
      int sel = corrupt ? 0 : is_aa[mol];
      packed = pos_ids[mol] | (sel << 12) | ((g ? 0 : 1) << 13);
    }
    *(int*)(sm + 16384 + tid*4) = packed;
  }
  __syncthreads();

  f32x4 acc[4][2];
  gemm4(sm, 0, (const __bf16*)(ws + W2T_OFF), mb0, lane, wave, acc);
  {
    const __bf16* PW = (const __bf16*)(ws + PW_OFF);
    const float* AAW = (const float*)(ws + AAW_OFF);
    #pragma unroll
    for (int m = 0; m < 4; ++m)
    #pragma unroll
    for (int r = 0; r < 4; ++r) {
      int row = m*16 + (lane >> 4)*4 + r;
      int packed = *(const int*)(sm + 16384 + row*4);
      int pid = packed & 0xFFF, sf = (packed >> 12) & 3;
      #pragma unroll
      for (int nf = 0; nf < 2; ++nf) {
        int col = wave*32 + nf*16 + (lane & 15);
        float v = acc[m][nf][r] + (float)PW[pid*128 + col] + AAW[sf*128 + col];
        acc[m][nf][r] = fmaxf(v, 0.f);
      }
    }
  }
  __syncthreads();
  stor4(sm, 0, acc, lane, wave, false);  // h1 over topo panel
  __syncthreads();

  gemm4(sm, 0, (const __bf16*)(ws + M1T_OFF), mb1, lane, wave, acc);
  stor4(sm, 16384, acc, lane, wave, true);
  __syncthreads();

  gemm4(sm, 16384, (const __bf16*)(ws + M2T_OFF), mb2, lane, wave, acc);
  #pragma unroll
  for (int m = 0; m < 4; ++m)
  #pragma unroll
  for (int nf = 0; nf < 2; ++nf)
  #pragma unroll
  for (int r = 0; r < 4; ++r) {
    int row = m*16 + (lane >> 4)*4 + r;
    int col = wave*32 + nf*16 + (lane & 15);
    int mol = r0 + row;
    if (mol < NBLK) out[(long)mol*128 + col] = scrub(acc[m][nf][r]);
  }
}

extern "C" void kernel_launch(void* const* d_in, const int* in_sizes, int n_in,
                              void* d_out, int out_size, void* d_ws, size_t ws_size,
                              hipStream_t stream) {
  if (ws_size < WS_NEED) return;   // diagnostic: absmax-fail instead of fault
  const int* A      = (const int*)d_in[0];
  const int* bonds  = (const int*)d_in[1];
  const void* gm    = d_in[3];
  const int* pos    = (const int*)d_in[4];
  const int* isaa   = (const int*)d_in[5];
  const float* cr   = (const float*)d_in[6];
  const float* atom_embed = (const float*)d_in[7];
  const float* bond_embed = (const float*)d_in[8];
  const float* aa_embed   = (const float*)d_in[9];
  const float* g1  = (const float*)d_in[10];
  const float* gb1 = (const float*)d_in[11];
  const float* g2  = (const float*)d_in[12];
  const float* gb2 = (const float*)d_in[13];
  const float* m0  = (const float*)d_in[14];
  const float* mb0 = (const float*)d_in[15];
  const float* m1  = (const float*)d_in[16];
  const float* mb1 = (const float*)d_in[17];
  const float* m2  = (const float*)d_in[18];
  const float* mb2 = (const float*)d_in[19];
  char* ws = (char*)d_ws;

  hipMemsetAsync(ws + START_OFF, 0, (size_t)(NATOM+1)*4, stream);
  k_sniff   <<<1, 256, 0, stream>>>(gm, ws);
  k_prep    <<<2885, 128, 0, stream>>>(atom_embed, bond_embed, m0, m1, m2,
                                       g2, gb2, aa_embed, gm, bonds, ws);
  k_scan1   <<<NBS, 256, 0, stream>>>(ws);
  k_scan2   <<<1, 256, 0, stream>>>(ws);
  k_scan3   <<<NBS, 256, 0, stream>>>(ws);
  k_scatter4<<<782, 256, 0, stream>>>(bonds, A, ws);
  k_prep2   <<<600, 128, 0, stream>>>(atom_embed, g1, gb1, ws);   // EW1, TW1
  k_gather2 <<<3125, 256, 0, stream>>>(ws, A);
  k_mlp3    <<<(NBLK + 63)/64, 256, 0, stream>>>(ws, pos, isaa, cr,
                                                 mb0, mb1, mb2, (float*)d_out);
}

// Round 15
// 140.564 us; speedup vs baseline: 1.9473x; 1.0475x over previous
//
#include <hip/hip_runtime.h>
#include <hip/hip_bf16.h>

#define NBLK  50000
#define NATOM 400000
#define NEDGE 800000
#define NSCB  196              // ceil(50000/256) scan blocks

typedef __bf16 bf16x8 __attribute__((ext_vector_type(8)));
typedef float  f32x4  __attribute__((ext_vector_type(4)));

// ---- workspace layout (bytes); fits proven WS_NEED = 18,403,840 ----
#define MSTART_OFF 0UL         // int32[50001]: per-MOL edge counts -> offsets
#define MCUR_OFF   200016UL    // int32[50000]: scatter cursors
#define MBS_OFF    400016UL    // int32[256]: scan block sums
#define EW1_OFF    401040UL    // f32[100][128] = emb@W1+b1
#define REC_OFF    452240UL    // u16[800000]: (pair*8 + dst&7), CSR by mol
#define T_OFF      2052240UL   // f32[500][128]: msg table; REWRITTEN to TW1 = T@W1
#define PW_OFF     2308240UL   // bf16[1024][128]: sinusoid @ W0[0:128]
#define W2T_OFF    2570384UL   // bf16[128][128]: (rs8*W2@W0[128:256])^T [n][k]
#define M1T_OFF    2603152UL   // bf16[128][128] mlp_w1^T
#define M2T_OFF    2635920UL   // bf16[128][128] mlp_w2^T
#define AAW_OFF    2668688UL   // f32[4][128]
#define GM_OFF     2670736UL   // u8[50000]
#define FLAG_OFF   2720752UL   // int32 sniff flag
#define TOPO_OFF   2720768UL   // bf16[50000][128] topo_pre
#define WS_NEED    18403840UL

#define RS8 0.35355339059327373f

#define MFMA(a,b,c) __builtin_amdgcn_mfma_f32_16x16x32_bf16((a),(b),(c),0,0,0)

__device__ inline f32x4 splat4(float v){ f32x4 r; r[0]=v; r[1]=v; r[2]=v; r[3]=v; return r; }
__device__ inline float scrub(float v){ return (v==v && v<1e30f && v>-1e30f) ? v : 0.f; }

// ---------------- dtype sniff for generate_mask (1 block) ----------------
__global__ void k_sniff(const void* gm_raw, char* ws) {
  __shared__ int big;
  if (threadIdx.x == 0) big = 0;
  __syncthreads();
  const unsigned* gw = (const unsigned*)gm_raw;
  for (int i = threadIdx.x; i < 12500; i += 256)
    if (gw[i] > 1u) big = 1;
  __syncthreads();
  if (threadIdx.x == 0) *(int*)(ws + FLAG_OFF) = big;
}

// ---- prep (merged): T, M1T/M2T, gm canon, PW, W2T', AAW, per-MOL edge COUNT ----
// blocks: [0,100) T, [100,116) transposes, [116,166) gm, [166,1190) PW,
// [1190,1318) W2T, [1318,1322) AAW, [1322,2885) count (reads RAW gm via flag)
__global__ void k_prep(const float* atom_embed, const float* bond_embed,
                       const float* m0, const float* m1, const float* m2,
                       const float* g2, const float* gb2, const float* aa_embed,
                       const void* gm_raw, const int* __restrict__ bonds, char* ws) {
  int b = blockIdx.x, t = threadIdx.x;
  if (b < 100) {                       // T[a*5+bond][c] = relu(ae + be), f32
    float ae = atom_embed[b*128 + t];
    float* T = (float*)(ws + T_OFF);
    for (int bo = 0; bo < 5; ++bo) {
      float v = ae + bond_embed[bo*128 + t];
      T[(b*5 + bo)*128 + t] = v > 0.f ? v : 0.f;
    }
  } else if (b < 116) {                // weight transposes f32 -> bf16 [n][k]
    int wb = b - 100;
    const float* src; __bf16* dst; int r0;
    if (wb < 8) { src = m1; dst = (__bf16*)(ws + M1T_OFF); r0 = wb*16; }
    else        { src = m2; dst = (__bf16*)(ws + M2T_OFF); r0 = (wb-8)*16; }
    for (int rr = 0; rr < 16; ++rr) {
      int r = r0 + rr;
      dst[t*128 + r] = (__bf16)src[r*128 + t];
    }
  } else if (b < 166) {                // gm canon: 50 blocks x 1000 elems
    int anyBig = *(const int*)(ws + FLAG_OFF);
    int base = (b - 116) * 1000;
    unsigned char* gu = (unsigned char*)(ws + GM_OFF);
    if (anyBig) {
      const unsigned char* gb = (const unsigned char*)gm_raw;
      for (int i = t; i < 1000; i += 128) gu[base+i] = gb[base+i] ? 1 : 0;
    } else {
      const int* gi = (const int*)gm_raw;
      for (int i = t; i < 1000; i += 128) gu[base+i] = gi[base+i] ? 1 : 0;
    }
  } else if (b < 1190) {               // PW[p][t] = sum_j s(p,j)*W0[j][t], bf16
    int p = b - 166;
    __shared__ float s[128];
    int c = t & 63;
    float invf = exp2f((float)c * -0.20762050593046012f);  // 10000^(-c/64)
    float ang = (float)p * invf;
    s[t] = (t < 64) ? __sinf(ang) : __cosf(ang);
    __syncthreads();
    float acc = 0.f;
    #pragma unroll 4
    for (int j = 0; j < 128; ++j) acc += s[j] * m0[j*128 + t];
    ((__bf16*)(ws + PW_OFF))[p*128 + t] = (__bf16)acc;
  } else if (b < 1318) {               // W2T[c][r] = rs8 * sum_j W2[r][j]*W0[128+j][c]
    int r = b - 1190;
    float acc = 0.f;
    #pragma unroll 4
    for (int j = 0; j < 128; ++j) acc += g2[r*128 + j] * m0[(128+j)*128 + t];
    ((__bf16*)(ws + W2T_OFF))[t*128 + r] = (__bf16)(acc * RS8);
  } else if (b < 1322) {               // AAW[sf][t], sf = sel + 2*f
    int sf = b - 1318, sel = sf & 1, f = sf >> 1;
    float acc = 0.f;
    #pragma unroll 4
    for (int j = 0; j < 128; ++j) acc += aa_embed[sel*128 + j] * m0[(256+j)*128 + t];
    if (f) {
      float cacc = 0.f;
      #pragma unroll 4
      for (int j = 0; j < 128; ++j) cacc += gb2[j] * m0[(128+j)*128 + t];
      acc += 8.0f * RS8 * cacc;
    }
    ((float*)(ws + AAW_OFF))[sf*128 + t] = acc;
  } else {                             // COUNT per mol: 4 edges/thread, raw gm
    int anyBig = *(const int*)(ws + FLAG_OFF);
    const unsigned char* g8 = (const unsigned char*)gm_raw;
    const int* g32 = (const int*)gm_raw;
    int base = ((b - 1322)*128 + t)*4;
    if (base < NEDGE) {
      const int4* bp = (const int4*)(bonds + (long)base*3);
      int4 w0 = bp[0], w1 = bp[1], w2 = bp[2];
      int srcs[4] = {w0.x, w0.w, w1.z, w2.y};
      int dsts[4] = {w0.y, w1.x, w1.w, w2.z};
      #pragma unroll
      for (int i = 0; i < 4; ++i) {
        int sm_ = srcs[i] >> 3, dm = dsts[i] >> 3;
        int bad = anyBig ? ((int)g8[sm_] | (int)g8[dm]) : (g32[sm_] | g32[dm]);
        if (!bad) atomicAdd((int*)(ws + MSTART_OFF) + dm, 1);
      }
    }
  }
}

// ------- prep2: EW1 = emb@W1+b1 (own region), TW1 = T@W1 in place over T -------
__global__ void k_prep2(const float* atom_embed, const float* g1, const float* gb1,
                        char* ws) {
  int b = blockIdx.x, t = threadIdx.x;
  float s0 = 0.f, s1 = 0.f, s2 = 0.f, s3 = 0.f;
  const float* row = (b < 100) ? (atom_embed + b*128) : ((float*)(ws + T_OFF) + (b-100)*128);
  #pragma unroll 4
  for (int k = 0; k < 128; k += 4) {
    s0 += row[k+0] * g1[(k+0)*128 + t];
    s1 += row[k+1] * g1[(k+1)*128 + t];
    s2 += row[k+2] * g1[(k+2)*128 + t];
    s3 += row[k+3] * g1[(k+3)*128 + t];
  }
  float s = (s0 + s1) + (s2 + s3);
  if (b < 100) {
    ((float*)(ws + EW1_OFF))[b*128 + t] = s + gb1[t];
  } else {
    __syncthreads();
    ((float*)(ws + T_OFF))[(b-100)*128 + t] = s;
  }
}

// ---------------- exclusive scan over 50000 mol counts ----------------
__global__ void k_scan1(char* ws) {
  __shared__ int s[256];
  int b = blockIdx.x, t = threadIdx.x, i = b*256 + t;
  int* cnt = (int*)(ws + MSTART_OFF);
  int v = (i < NBLK) ? cnt[i] : 0;
  s[t] = v; __syncthreads();
  for (int d = 1; d < 256; d <<= 1) {
    int x = (t >= d) ? s[t-d] : 0;
    __syncthreads(); s[t] += x; __syncthreads();
  }
  if (i < NBLK) cnt[i] = s[t] - v;
  if (t == 255) ((int*)(ws + MBS_OFF))[b] = s[255];
}
__global__ void k_scan2(char* ws) {
  __shared__ int s[256];
  int t = threadIdx.x;
  int* bs = (int*)(ws + MBS_OFF);
  int v = (t < NSCB) ? bs[t] : 0;
  s[t] = v; __syncthreads();
  for (int d = 1; d < 256; d <<= 1) {
    int x = (t >= d) ? s[t-d] : 0;
    __syncthreads(); s[t] += x; __syncthreads();
  }
  if (t < NSCB) bs[t] = s[t] - v;
  if (t == 255) ((int*)(ws + MSTART_OFF))[NBLK] = s[255];  // grand total
}
__global__ void k_scan3(char* ws) {
  int b = blockIdx.x, i = b*256 + threadIdx.x;
  if (i >= NBLK) return;
  int* start = (int*)(ws + MSTART_OFF);
  int v = start[i] + ((int*)(ws + MBS_OFF))[b];
  start[i] = v;
  ((int*)(ws + MCUR_OFF))[i] = v;
}

// ---------------- scatter mol-CSR records: 4 edges/thread ----------------
__global__ void k_scatter4(const int* __restrict__ bonds, const int* __restrict__ A, char* ws) {
  int base = (blockIdx.x*256 + threadIdx.x)*4;
  if (base >= NEDGE) return;
  const unsigned char* gm = (const unsigned char*)(ws + GM_OFF);
  const int4* bp = (const int4*)(bonds + (long)base*3);
  int4 w0 = bp[0], w1 = bp[1], w2 = bp[2];
  int srcs[4] = {w0.x, w0.w, w1.z, w2.y};
  int dsts[4] = {w0.y, w1.x, w1.w, w2.z};
  int bts[4]  = {w0.z, w1.y, w2.x, w2.w};
  #pragma unroll
  for (int i = 0; i < 4; ++i) {
    if (gm[srcs[i] >> 3] | gm[dsts[i] >> 3]) continue;
    int slot = atomicAdd((int*)(ws + MCUR_OFF) + (dsts[i] >> 3), 1);
    if (slot >= 0 && slot < NEDGE)
      ((unsigned short*)(ws + REC_OFF))[slot] =
        (unsigned short)((A[srcs[i]]*5 + bts[i])*8 + (dsts[i] & 7));
  }
}

// ---- gather3: wave-per-mol, zero LDS. lane = (atom a_l 0..7) x (col-eighth q8) ----
// u[16] = relu(EW1[A] + sum_{edges, dl==a_l} TW1[p]); 3x shfl_xor -> mol sum;
// lanes a_l==0 write the bf16 row. Wave-uniform edge loop (scalar s0/s1/rec).
__launch_bounds__(256, 8)
__global__ void k_gather3(char* ws, const int* __restrict__ A) {
  const int tid = threadIdx.x;
  const int lane = tid & 63, wid = tid >> 6;
  const int mol = blockIdx.x*4 + wid;
  const int a_l = lane >> 3, q8 = lane & 7;
  const unsigned char* gm = (const unsigned char*)(ws + GM_OFF);

  f32x4 u0 = splat4(0.f), u1 = splat4(0.f), u2 = splat4(0.f), u3 = splat4(0.f);
  if (!gm[mol]) {
    const int* start = (const int*)(ws + MSTART_OFF);
    const unsigned short* rec = (const unsigned short*)(ws + REC_OFF);
    const float* EW1 = (const float*)(ws + EW1_OFF);
    const float* TW1 = (const float*)(ws + T_OFF);
    int s0 = start[mol], s1 = start[mol+1];          // wave-uniform
    if (s0 < 0) s0 = 0;
    if (s1 > NEDGE) s1 = NEDGE;
    int aT = A[mol*8 + a_l];
    const f32x4* ep = (const f32x4*)(EW1 + aT*128 + q8*16);
    u0 = ep[0]; u1 = ep[1]; u2 = ep[2]; u3 = ep[3];
    for (int e = s0; e < s1; ++e) {
      int rv = rec[e];                               // uniform -> scalar load
      int p = rv >> 3;
      if (p >= 500) p = 0;                           // defensive
      if ((rv & 7) == a_l) {
        const f32x4* tp = (const f32x4*)(TW1 + p*128 + q8*16);
        u0 += tp[0]; u1 += tp[1]; u2 += tp[2]; u3 += tp[3];
      }
    }
  }
  // relu + cross-atom reduce (lane bits 3..5) -> every lane holds mol sum seg
  #pragma unroll
  for (int k = 0; k < 4; ++k) {
    float x0 = fmaxf(u0[k], 0.f), x1 = fmaxf(u1[k], 0.f);
    float x2 = fmaxf(u2[k], 0.f), x3 = fmaxf(u3[k], 0.f);
    x0 += __shfl_xor(x0, 8);  x1 += __shfl_xor(x1, 8);
    x2 += __shfl_xor(x2, 8);  x3 += __shfl_xor(x3, 8);
    x0 += __shfl_xor(x0, 16); x1 += __shfl_xor(x1, 16);
    x2 += __shfl_xor(x2, 16); x3 += __shfl_xor(x3, 16);
    x0 += __shfl_xor(x0, 32); x1 += __shfl_xor(x1, 32);
    x2 += __shfl_xor(x2, 32); x3 += __shfl_xor(x3, 32);
    u0[k] = x0; u1[k] = x1; u2[k] = x2; u3[k] = x3;
  }
  if (a_l == 0) {
    bf16x8 o0, o1;
    #pragma unroll
    for (int k = 0; k < 4; ++k) {
      o0[k] = (__bf16)u0[k]; o0[k+4] = (__bf16)u1[k];
      o1[k] = (__bf16)u2[k]; o1[k+4] = (__bf16)u3[k];
    }
    char* dst = ws + TOPO_OFF + (long)mol*256 + q8*32;
    *(bf16x8*)dst = o0;
    *(bf16x8*)(dst + 16) = o1;
  }
}

// ------------- GEMM core: 64x128 tile, 4 waves, K=128, single LDS panel -------------
__device__ inline void gemm4(const char* sm, int aoff, const __bf16* wt,
                             const float* bias, int lane, int wave, f32x4 acc[4][2]) {
  const int colA = wave*32 + (lane & 15);
  const int k0   = (lane >> 4) * 8;
  float bb0 = bias[colA], bb1 = bias[colA + 16];
  #pragma unroll
  for (int m = 0; m < 4; ++m) { acc[m][0] = splat4(bb0); acc[m][1] = splat4(bb1); }
  #pragma unroll
  for (int kb = 0; kb < 4; ++kb) {
    bf16x8 b0 = *(const bf16x8*)(wt + colA*128 + kb*32 + k0);
    bf16x8 b1 = *(const bf16x8*)(wt + (colA+16)*128 + kb*32 + k0);
    #pragma unroll
    for (int m = 0; m < 4; ++m) {
      int rA = m*16 + (lane & 15);
      int byte = aoff + rA*256 + (((kb*64) + k0*2) ^ ((rA & 7) << 4));
      bf16x8 a = *(const bf16x8*)(sm + byte);
      acc[m][0] = MFMA(a, b0, acc[m][0]);
      acc[m][1] = MFMA(a, b1, acc[m][1]);
    }
  }
}

__device__ inline void stor4(char* sm, int off, f32x4 acc[4][2],
                             int lane, int wave, bool do_relu) {
  #pragma unroll
  for (int m = 0; m < 4; ++m)
  #pragma unroll
  for (int nf = 0; nf < 2; ++nf)
  #pragma unroll
  for (int r = 0; r < 4; ++r) {
    float v = acc[m][nf][r];
    if (do_relu && v < 0.f) v = 0.f;
    int row = m*16 + (lane >> 4)*4 + r;
    int col = wave*32 + nf*16 + (lane & 15);
    int byte = off + row*256 + ((col*2) ^ ((row & 7) << 4));
    *(__bf16*)(sm + byte) = (__bf16)v;
  }
}

// ---- mlp3: stage topo_pre -> GEMM_T(K=128)+epilogue(PW/AAW) -> GEMM1 -> GEMM3 ----
__launch_bounds__(256)
__global__ void k_mlp3(char* ws, const int* __restrict__ pos_ids,
                       const int* __restrict__ is_aa, const float* cr,
                       const float* mb0, const float* mb1, const float* mb2,
                       float* __restrict__ out) {
  __shared__ __align__(16) char sm[32768];
  const int tid = threadIdx.x, lane = tid & 63, wave = tid >> 6;
  const int r0 = blockIdx.x * 64;
  const unsigned char* gm = (const unsigned char*)(ws + GM_OFF);
  const __bf16* topo_pre = (const __bf16*)(ws + TOPO_OFF);

  for (int i = 0; i < 4; ++i) {          // stage topo panel @0
    int idx = tid + i*256;
    int row = idx >> 4, c = idx & 15;
    int mol = r0 + row;
    bf16x8 v;
    #pragma unroll
    for (int j = 0; j < 8; ++j) v[j] = (__bf16)0.f;
    if (mol < NBLK) v = *(const bf16x8*)(topo_pre + (long)mol*128 + c*8);
    int byte = row*256 + ((c*16) ^ ((row & 7) << 4));
    *(bf16x8*)(sm + byte) = v;
  }
  if (tid < 64) {                        // per-row scalars @16384
    int mol = r0 + tid, packed = 0;
    if (mol < NBLK) {
      int g = gm[mol];
      int corrupt = g && (cr[mol] < 0.1f);
      int sel = corrupt ? 0 : is_aa[mol];
      packed = pos_ids[mol] | (sel << 12) | ((g ? 0 : 1) << 13);
    }
    *(int*)(sm + 16384 + tid*4) = packed;
  }
  __syncthreads();

  f32x4 acc[4][2];
  gemm4(sm, 0, (const __bf16*)(ws + W2T_OFF), mb0, lane, wave, acc);
  {
    const __bf16* PW = (const __bf16*)(ws + PW_OFF);
    const float* AAW = (const float*)(ws + AAW_OFF);
    #pragma unroll
    for (int m = 0; m < 4; ++m)
    #pragma unroll
    for (int r = 0; r < 4; ++r) {
      int row = m*16 + (lane >> 4)*4 + r;
      int packed = *(const int*)(sm + 16384 + row*4);
      int pid = packed & 0xFFF, sf = (packed >> 12) & 3;
      #pragma unroll
      for (int nf = 0; nf < 2; ++nf) {
        int col = wave*32 + nf*16 + (lane & 15);
        float v = acc[m][nf][r] + (float)PW[pid*128 + col] + AAW[sf*128 + col];
        acc[m][nf][r] = fmaxf(v, 0.f);
      }
    }
  }
  __syncthreads();
  stor4(sm, 0, acc, lane, wave, false);  // h1 over topo panel
  __syncthreads();

  gemm4(sm, 0, (const __bf16*)(ws + M1T_OFF), mb1, lane, wave, acc);
  stor4(sm, 16384, acc, lane, wave, true);
  __syncthreads();

  gemm4(sm, 16384, (const __bf16*)(ws + M2T_OFF), mb2, lane, wave, acc);
  #pragma unroll
  for (int m = 0; m < 4; ++m)
  #pragma unroll
  for (int nf = 0; nf < 2; ++nf)
  #pragma unroll
  for (int r = 0; r < 4; ++r) {
    int row = m*16 + (lane >> 4)*4 + r;
    int col = wave*32 + nf*16 + (lane & 15);
    int mol = r0 + row;
    if (mol < NBLK) out[(long)mol*128 + col] = scrub(acc[m][nf][r]);
  }
}

extern "C" void kernel_launch(void* const* d_in, const int* in_sizes, int n_in,
                              void* d_out, int out_size, void* d_ws, size_t ws_size,
                              hipStream_t stream) {
  if (ws_size < WS_NEED) return;   // diagnostic: absmax-fail instead of fault
  const int* A      = (const int*)d_in[0];
  const int* bonds  = (const int*)d_in[1];
  const void* gm    = d_in[3];
  const int* pos    = (const int*)d_in[4];
  const int* isaa   = (const int*)d_in[5];
  const float* cr   = (const float*)d_in[6];
  const float* atom_embed = (const float*)d_in[7];
  const float* bond_embed = (const float*)d_in[8];
  const float* aa_embed   = (const float*)d_in[9];
  const float* g1  = (const float*)d_in[10];
  const float* gb1 = (const float*)d_in[11];
  const float* g2  = (const float*)d_in[12];
  const float* gb2 = (const float*)d_in[13];
  const float* m0  = (const float*)d_in[14];
  const float* mb0 = (const float*)d_in[15];
  const float* m1  = (const float*)d_in[16];
  const float* mb1 = (const float*)d_in[17];
  const float* m2  = (const float*)d_in[18];
  const float* mb2 = (const float*)d_in[19];
  char* ws = (char*)d_ws;

  hipMemsetAsync(ws + MSTART_OFF, 0, (size_t)(NBLK+1)*4, stream);
  k_sniff   <<<1, 256, 0, stream>>>(gm, ws);
  k_prep    <<<2885, 128, 0, stream>>>(atom_embed, bond_embed, m0, m1, m2,
                                       g2, gb2, aa_embed, gm, bonds, ws);
  k_scan1   <<<NSCB, 256, 0, stream>>>(ws);
  k_scan2   <<<1, 256, 0, stream>>>(ws);
  k_scan3   <<<NSCB, 256, 0, stream>>>(ws);
  k_scatter4<<<782, 256, 0, stream>>>(bonds, A, ws);
  k_prep2   <<<600, 128, 0, stream>>>(atom_embed, g1, gb1, ws);   // EW1, TW1
  k_gather3 <<<NBLK/4, 256, 0, stream>>>(ws, A);
  k_mlp3    <<<(NBLK + 63)/64, 256, 0, stream>>>(ws, pos, isaa, cr,
                                                 mb0, mb1, mb2, (float*)d_out);
}

// Round 16
// 123.564 us; speedup vs baseline: 2.2152x; 1.1376x over previous
//
#include <hip/hip_runtime.h>
#include <hip/hip_bf16.h>

#define NBLK  50000
#define NATOM 400000
#define NEDGE 800000
#define CAP   40               // max tracked in-edges per mol (Poisson(8): P(>40)~1e-14)

typedef __bf16 bf16x8 __attribute__((ext_vector_type(8)));
typedef float  f32x4  __attribute__((ext_vector_type(4)));

// ---- workspace layout (bytes); total 17,719,712 < proven 18,403,840 ----
#define MCNT_OFF 0UL           // int32[50000]: per-mol edge cursors (memset 0)
#define EW1_OFF  200000UL      // f32[100][128] = emb@W1+b1
#define REC_OFF  251200UL      // u16[50000][40]: (pair*8 + dst&7), direct slots
#define T_OFF    4251200UL     // f32[500][128]: msg table; REWRITTEN to TW1 = T@W1
#define PW_OFF   4507200UL     // bf16[1024][128]: sinusoid @ W0[0:128]
#define W2T_OFF  4769344UL     // bf16[128][128]: (rs8*W2@W0[128:256])^T [n][k]
#define M1T_OFF  4802112UL     // bf16[128][128] mlp_w1^T
#define M2T_OFF  4834880UL     // bf16[128][128] mlp_w2^T
#define AAW_OFF  4867648UL     // f32[4][128]
#define GM_OFF   4869696UL     // u8[50000]
#define FLAG_OFF 4919696UL     // int32 sniff flag
#define TOPO_OFF 4919712UL     // bf16[50000][128] topo_pre
#define WS_NEED  18403840UL

#define RS8 0.35355339059327373f

#define MFMA(a,b,c) __builtin_amdgcn_mfma_f32_16x16x32_bf16((a),(b),(c),0,0,0)

__device__ inline f32x4 splat4(float v){ f32x4 r; r[0]=v; r[1]=v; r[2]=v; r[3]=v; return r; }
__device__ inline float scrub(float v){ return (v==v && v<1e30f && v>-1e30f) ? v : 0.f; }

// ---------------- dtype sniff for generate_mask (1 block) ----------------
__global__ void k_sniff(const void* gm_raw, char* ws) {
  __shared__ int big;
  if (threadIdx.x == 0) big = 0;
  __syncthreads();
  const unsigned* gw = (const unsigned*)gm_raw;
  for (int i = threadIdx.x; i < 12500; i += 256)
    if (gw[i] > 1u) big = 1;
  __syncthreads();
  if (threadIdx.x == 0) *(int*)(ws + FLAG_OFF) = big;
}

// ---- prep (merged): T, M1T/M2T, gm canon, PW, W2T', AAW ----
// blocks: [0,100) T, [100,116) transposes, [116,166) gm, [166,1190) PW,
// [1190,1318) W2T, [1318,1322) AAW
__global__ void k_prep(const float* atom_embed, const float* bond_embed,
                       const float* m0, const float* m1, const float* m2,
                       const float* g2, const float* gb2, const float* aa_embed,
                       const void* gm_raw, char* ws) {
  int b = blockIdx.x, t = threadIdx.x;
  if (b < 100) {                       // T[a*5+bond][c] = relu(ae + be), f32
    float ae = atom_embed[b*128 + t];
    float* T = (float*)(ws + T_OFF);
    for (int bo = 0; bo < 5; ++bo) {
      float v = ae + bond_embed[bo*128 + t];
      T[(b*5 + bo)*128 + t] = v > 0.f ? v : 0.f;
    }
  } else if (b < 116) {                // weight transposes f32 -> bf16 [n][k]
    int wb = b - 100;
    const float* src; __bf16* dst; int r0;
    if (wb < 8) { src = m1; dst = (__bf16*)(ws + M1T_OFF); r0 = wb*16; }
    else        { src = m2; dst = (__bf16*)(ws + M2T_OFF); r0 = (wb-8)*16; }
    for (int rr = 0; rr < 16; ++rr) {
      int r = r0 + rr;
      dst[t*128 + r] = (__bf16)src[r*128 + t];
    }
  } else if (b < 166) {                // gm canon: 50 blocks x 1000 elems
    int anyBig = *(const int*)(ws + FLAG_OFF);
    int base = (b - 116) * 1000;
    unsigned char* gu = (unsigned char*)(ws + GM_OFF);
    if (anyBig) {
      const unsigned char* gb = (const unsigned char*)gm_raw;
      for (int i = t; i < 1000; i += 128) gu[base+i] = gb[base+i] ? 1 : 0;
    } else {
      const int* gi = (const int*)gm_raw;
      for (int i = t; i < 1000; i += 128) gu[base+i] = gi[base+i] ? 1 : 0;
    }
  } else if (b < 1190) {               // PW[p][t] = sum_j s(p,j)*W0[j][t], bf16
    int p = b - 166;
    __shared__ float s[128];
    int c = t & 63;
    float invf = exp2f((float)c * -0.20762050593046012f);  // 10000^(-c/64)
    float ang = (float)p * invf;
    s[t] = (t < 64) ? __sinf(ang) : __cosf(ang);
    __syncthreads();
    float acc = 0.f;
    #pragma unroll 4
    for (int j = 0; j < 128; ++j) acc += s[j] * m0[j*128 + t];
    ((__bf16*)(ws + PW_OFF))[p*128 + t] = (__bf16)acc;
  } else if (b < 1318) {               // W2T[c][r] = rs8 * sum_j W2[r][j]*W0[128+j][c]
    int r = b - 1190;
    float acc = 0.f;
    #pragma unroll 4
    for (int j = 0; j < 128; ++j) acc += g2[r*128 + j] * m0[(128+j)*128 + t];
    ((__bf16*)(ws + W2T_OFF))[t*128 + r] = (__bf16)(acc * RS8);
  } else {                             // AAW[sf][t], sf = sel + 2*f
    int sf = b - 1318, sel = sf & 1, f = sf >> 1;
    float acc = 0.f;
    #pragma unroll 4
    for (int j = 0; j < 128; ++j) acc += aa_embed[sel*128 + j] * m0[(256+j)*128 + t];
    if (f) {
      float cacc = 0.f;
      #pragma unroll 4
      for (int j = 0; j < 128; ++j) cacc += gb2[j] * m0[(128+j)*128 + t];
      acc += 8.0f * RS8 * cacc;
    }
    ((float*)(ws + AAW_OFF))[sf*128 + t] = acc;
  }
}

// ------- prep2: EW1 = emb@W1+b1, TW1 = T@W1 (in place over T) -------
__global__ void k_prep2(const float* atom_embed, const float* g1, const float* gb1,
                        char* ws) {
  int b = blockIdx.x, t = threadIdx.x;
  float s0 = 0.f, s1 = 0.f, s2 = 0.f, s3 = 0.f;
  const float* row = (b < 100) ? (atom_embed + b*128) : ((float*)(ws + T_OFF) + (b-100)*128);
  #pragma unroll 4
  for (int k = 0; k < 128; k += 4) {
    s0 += row[k+0] * g1[(k+0)*128 + t];
    s1 += row[k+1] * g1[(k+1)*128 + t];
    s2 += row[k+2] * g1[(k+2)*128 + t];
    s3 += row[k+3] * g1[(k+3)*128 + t];
  }
  float s = (s0 + s1) + (s2 + s3);
  if (b < 100) {
    ((float*)(ws + EW1_OFF))[b*128 + t] = s + gb1[t];
  } else {
    __syncthreads();
    ((float*)(ws + T_OFF))[(b-100)*128 + t] = s;
  }
}

// ---------------- scatter direct-slot records: 4 edges/thread ----------------
__global__ void k_scatter4(const int* __restrict__ bonds, const int* __restrict__ A, char* ws) {
  int base = (blockIdx.x*256 + threadIdx.x)*4;
  if (base >= NEDGE) return;
  const unsigned char* gm = (const unsigned char*)(ws + GM_OFF);
  const int4* bp = (const int4*)(bonds + (long)base*3);
  int4 w0 = bp[0], w1 = bp[1], w2 = bp[2];
  int srcs[4] = {w0.x, w0.w, w1.z, w2.y};
  int dsts[4] = {w0.y, w1.x, w1.w, w2.z};
  int bts[4]  = {w0.z, w1.y, w2.x, w2.w};
  #pragma unroll
  for (int i = 0; i < 4; ++i) {
    if (gm[srcs[i] >> 3] | gm[dsts[i] >> 3]) continue;
    int mol = dsts[i] >> 3;
    int slot = atomicAdd((int*)(ws + MCNT_OFF) + mol, 1);
    if (slot >= 0 && slot < CAP)
      ((unsigned short*)(ws + REC_OFF))[mol*CAP + slot] =
        (unsigned short)((A[srcs[i]]*5 + bts[i])*8 + (dsts[i] & 7));
  }
}

// ---- gather4: wave-per-mol, zero LDS, 2 independent edge chains ----
// lane = (atom a_l 0..7) x (col-eighth q8); rec read as u32 pairs (uniform).
__launch_bounds__(256, 8)
__global__ void k_gather4(char* ws, const int* __restrict__ A) {
  const int tid = threadIdx.x;
  const int lane = tid & 63, wid = tid >> 6;
  const int mol = blockIdx.x*4 + wid;
  const int a_l = lane >> 3, q8 = lane & 7;
  const unsigned char* gm = (const unsigned char*)(ws + GM_OFF);

  f32x4 a0 = splat4(0.f), a1 = splat4(0.f), a2 = splat4(0.f), a3 = splat4(0.f);
  f32x4 b0 = splat4(0.f), b1 = splat4(0.f), b2 = splat4(0.f), b3 = splat4(0.f);
  if (!gm[mol]) {
    const int* cnt = (const int*)(ws + MCNT_OFF);
    const unsigned* rec32 = (const unsigned*)(ws + REC_OFF);
    const unsigned short* rec16 = (const unsigned short*)(ws + REC_OFF);
    const float* EW1 = (const float*)(ws + EW1_OFF);
    const float* TW1 = (const float*)(ws + T_OFF);
    int n = cnt[mol];
    if (n > CAP) n = CAP;
    if (n < 0) n = 0;
    int aT = A[mol*8 + a_l];
    const f32x4* ep = (const f32x4*)(EW1 + aT*128 + q8*16);
    a0 = ep[0]; a1 = ep[1]; a2 = ep[2]; a3 = ep[3];
    const int half = n >> 1;
    const int base32 = mol*(CAP/2);
    for (int i = 0; i < half; ++i) {
      unsigned pr = rec32[base32 + i];             // two records, one uniform load
      int rv0 = pr & 0xFFFF, rv1 = pr >> 16;
      int p0 = rv0 >> 3, p1 = rv1 >> 3;
      if (p0 < 500 && (rv0 & 7) == a_l) {          // chain A
        const f32x4* tp = (const f32x4*)(TW1 + p0*128 + q8*16);
        a0 += tp[0]; a1 += tp[1]; a2 += tp[2]; a3 += tp[3];
      }
      if (p1 < 500 && (rv1 & 7) == a_l) {          // chain B (independent)
        const f32x4* tp = (const f32x4*)(TW1 + p1*128 + q8*16);
        b0 += tp[0]; b1 += tp[1]; b2 += tp[2]; b3 += tp[3];
      }
    }
    if (n & 1) {
      int rv = rec16[mol*CAP + n - 1];
      int p = rv >> 3;
      if (p < 500 && (rv & 7) == a_l) {
        const f32x4* tp = (const f32x4*)(TW1 + p*128 + q8*16);
        b0 += tp[0]; b1 += tp[1]; b2 += tp[2]; b3 += tp[3];
      }
    }
  }
  // combine chains, relu, cross-atom reduce (lane bits 3..5)
  #pragma unroll
  for (int k = 0; k < 4; ++k) {
    float x0 = fmaxf(a0[k] + b0[k], 0.f), x1 = fmaxf(a1[k] + b1[k], 0.f);
    float x2 = fmaxf(a2[k] + b2[k], 0.f), x3 = fmaxf(a3[k] + b3[k], 0.f);
    x0 += __shfl_xor(x0, 8);  x1 += __shfl_xor(x1, 8);
    x2 += __shfl_xor(x2, 8);  x3 += __shfl_xor(x3, 8);
    x0 += __shfl_xor(x0, 16); x1 += __shfl_xor(x1, 16);
    x2 += __shfl_xor(x2, 16); x3 += __shfl_xor(x3, 16);
    x0 += __shfl_xor(x0, 32); x1 += __shfl_xor(x1, 32);
    x2 += __shfl_xor(x2, 32); x3 += __shfl_xor(x3, 32);
    a0[k] = x0; a1[k] = x1; a2[k] = x2; a3[k] = x3;
  }
  if (a_l == 0) {
    bf16x8 o0, o1;
    #pragma unroll
    for (int k = 0; k < 4; ++k) {
      o0[k] = (__bf16)a0[k]; o0[k+4] = (__bf16)a1[k];
      o1[k] = (__bf16)a2[k]; o1[k+4] = (__bf16)a3[k];
    }
    char* dst = ws + TOPO_OFF + (long)mol*256 + q8*32;
    *(bf16x8*)dst = o0;
    *(bf16x8*)(dst + 16) = o1;
  }
}

// ------------- GEMM core: 64x128 tile, 4 waves, K=128, single LDS panel -------------
__device__ inline void gemm4(const char* sm, int aoff, const __bf16* wt,
                             const float* bias, int lane, int wave, f32x4 acc[4][2]) {
  const int colA = wave*32 + (lane & 15);
  const int k0   = (lane >> 4) * 8;
  float bb0 = bias[colA], bb1 = bias[colA + 16];
  #pragma unroll
  for (int m = 0; m < 4; ++m) { acc[m][0] = splat4(bb0); acc[m][1] = splat4(bb1); }
  #pragma unroll
  for (int kb = 0; kb < 4; ++kb) {
    bf16x8 b0 = *(const bf16x8*)(wt + colA*128 + kb*32 + k0);
    bf16x8 b1 = *(const bf16x8*)(wt + (colA+16)*128 + kb*32 + k0);
    #pragma unroll
    for (int m = 0; m < 4; ++m) {
      int rA = m*16 + (lane & 15);
      int byte = aoff + rA*256 + (((kb*64) + k0*2) ^ ((rA & 7) << 4));
      bf16x8 a = *(const bf16x8*)(sm + byte);
      acc[m][0] = MFMA(a, b0, acc[m][0]);
      acc[m][1] = MFMA(a, b1, acc[m][1]);
    }
  }
}

__device__ inline void stor4(char* sm, int off, f32x4 acc[4][2],
                             int lane, int wave, bool do_relu) {
  #pragma unroll
  for (int m = 0; m < 4; ++m)
  #pragma unroll
  for (int nf = 0; nf < 2; ++nf)
  #pragma unroll
  for (int r = 0; r < 4; ++r) {
    float v = acc[m][nf][r];
    if (do_relu && v < 0.f) v = 0.f;
    int row = m*16 + (lane >> 4)*4 + r;
    int col = wave*32 + nf*16 + (lane & 15);
    int byte = off + row*256 + ((col*2) ^ ((row & 7) << 4));
    *(__bf16*)(sm + byte) = (__bf16)v;
  }
}

// ---- mlp3: stage topo_pre -> GEMM_T(K=128)+epilogue(PW/AAW) -> GEMM1 -> GEMM3 ----
__launch_bounds__(256)
__global__ void k_mlp3(char* ws, const int* __restrict__ pos_ids,
                       const int* __restrict__ is_aa, const float* cr,
                       const float* mb0, const float* mb1, const float* mb2,
                       float* __restrict__ out) {
  __shared__ __align__(16) char sm[32768];
  const int tid = threadIdx.x, lane = tid & 63, wave = tid >> 6;
  const int r0 = blockIdx.x * 64;
  const unsigned char* gm = (const unsigned char*)(ws + GM_OFF);
  const __bf16* topo_pre = (const __bf16*)(ws + TOPO_OFF);

  for (int i = 0; i < 4; ++i) {          // stage topo panel @0
    int idx = tid + i*256;
    int row = idx >> 4, c = idx & 15;
    int mol = r0 + row;
    bf16x8 v;
    #pragma unroll
    for (int j = 0; j < 8; ++j) v[j] = (__bf16)0.f;
    if (mol < NBLK) v = *(const bf16x8*)(topo_pre + (long)mol*128 + c*8);
    int byte = row*256 + ((c*16) ^ ((row & 7) << 4));
    *(bf16x8*)(sm + byte) = v;
  }
  if (tid < 64) {                        // per-row scalars @16384
    int mol = r0 + tid, packed = 0;
    if (mol < NBLK) {
      int g = gm[mol];
      int corrupt = g && (cr[mol] < 0.1f);
      int sel = corrupt ? 0 : is_aa[mol];
      packed = pos_ids[mol] | (sel << 12) | ((g ? 0 : 1) << 13);
    }
    *(int*)(sm + 16384 + tid*4) = packed;
  }
  __syncthreads();

  f32x4 acc[4][2];
  gemm4(sm, 0, (const __bf16*)(ws + W2T_OFF), mb0, lane, wave, acc);
  {
    const __bf16* PW = (const __bf16*)(ws + PW_OFF);
    const float* AAW = (const float*)(ws + AAW_OFF);
    #pragma unroll
    for (int m = 0; m < 4; ++m)
    #pragma unroll
    for (int r = 0; r < 4; ++r) {
      int row = m*16 + (lane >> 4)*4 + r;
      int packed = *(const int*)(sm + 16384 + row*4);
      int pid = packed & 0xFFF, sf = (packed >> 12) & 3;
      #pragma unroll
      for (int nf = 0; nf < 2; ++nf) {
        int col = wave*32 + nf*16 + (lane & 15);
        float v = acc[m][nf][r] + (float)PW[pid*128 + col] + AAW[sf*128 + col];
        acc[m][nf][r] = fmaxf(v, 0.f);
      }
    }
  }
  __syncthreads();
  stor4(sm, 0, acc, lane, wave, false);  // h1 over topo panel
  __syncthreads();

  gemm4(sm, 0, (const __bf16*)(ws + M1T_OFF), mb1, lane, wave, acc);
  stor4(sm, 16384, acc, lane, wave, true);
  __syncthreads();

  gemm4(sm, 16384, (const __bf16*)(ws + M2T_OFF), mb2, lane, wave, acc);
  #pragma unroll
  for (int m = 0; m < 4; ++m)
  #pragma unroll
  for (int nf = 0; nf < 2; ++nf)
  #pragma unroll
  for (int r = 0; r < 4; ++r) {
    int row = m*16 + (lane >> 4)*4 + r;
    int col = wave*32 + nf*16 + (lane & 15);
    int mol = r0 + row;
    if (mol < NBLK) out[(long)mol*128 + col] = scrub(acc[m][nf][r]);
  }
}

extern "C" void kernel_launch(void* const* d_in, const int* in_sizes, int n_in,
                              void* d_out, int out_size, void* d_ws, size_t ws_size,
                              hipStream_t stream) {
  if (ws_size < WS_NEED) return;   // diagnostic: absmax-fail instead of fault
  const int* A      = (const int*)d_in[0];
  const int* bonds  = (const int*)d_in[1];
  const void* gm    = d_in[3];
  const int* pos    = (const int*)d_in[4];
  const int* isaa   = (const int*)d_in[5];
  const float* cr   = (const float*)d_in[6];
  const float* atom_embed = (const float*)d_in[7];
  const float* bond_embed = (const float*)d_in[8];
  const float* aa_embed   = (const float*)d_in[9];
  const float* g1  = (const float*)d_in[10];
  const float* gb1 = (const float*)d_in[11];
  const float* g2  = (const float*)d_in[12];
  const float* gb2 = (const float*)d_in[13];
  const float* m0  = (const float*)d_in[14];
  const float* mb0 = (const float*)d_in[15];
  const float* m1  = (const float*)d_in[16];
  const float* mb1 = (const float*)d_in[17];
  const float* m2  = (const float*)d_in[18];
  const float* mb2 = (const float*)d_in[19];
  char* ws = (char*)d_ws;

  hipMemsetAsync(ws + MCNT_OFF, 0, (size_t)NBLK*4, stream);
  k_sniff   <<<1, 256, 0, stream>>>(gm, ws);
  k_prep    <<<1322, 128, 0, stream>>>(atom_embed, bond_embed, m0, m1, m2,
                                       g2, gb2, aa_embed, gm, ws);
  k_scatter4<<<782, 256, 0, stream>>>(bonds, A, ws);
  k_prep2   <<<600, 128, 0, stream>>>(atom_embed, g1, gb1, ws);   // EW1, TW1
  k_gather4 <<<NBLK/4, 256, 0, stream>>>(ws, A);
  k_mlp3    <<<(NBLK + 63)/64, 256, 0, stream>>>(ws, pos, isaa, cr,
                                                 mb0, mb1, mb2, (float*)d_out);
}

// Round 17
// 113.649 us; speedup vs baseline: 2.4084x; 1.0872x over previous
//
#include <hip/hip_runtime.h>
#include <hip/hip_bf16.h>

#define NBLK  50000
#define NATOM 400000
#define NEDGE 800000
#define CAP   40               // max tracked in-edges per mol (Poisson(~4): P(>40)~1e-20)

typedef __bf16 bf16x8 __attribute__((ext_vector_type(8)));
typedef float  f32x4  __attribute__((ext_vector_type(4)));

// ---- workspace layout (bytes); total 17,719,712 < proven 18,403,840 ----
#define MCNT_OFF 0UL           // int32[50000]: per-mol edge cursors (memset 0)
#define EW1_OFF  200000UL      // f32[100][128] = emb@W1+b1
#define REC_OFF  251200UL      // u16[50000][40]: (pair*8 + dst&7), direct slots
#define T_OFF    4251200UL     // f32[500][128]: msg table; REWRITTEN to TW1 = T@W1
#define PW_OFF   4507200UL     // bf16[1024][128]: sinusoid @ W0[0:128]
#define W2T_OFF  4769344UL     // bf16[128][128]: (rs8*W2@W0[128:256])^T [n][k]
#define M1T_OFF  4802112UL     // bf16[128][128] mlp_w1^T
#define M2T_OFF  4834880UL     // bf16[128][128] mlp_w2^T
#define AAW_OFF  4867648UL     // f32[4][128]
#define GM_OFF   4869696UL     // u8[50000]
#define FLAG_OFF 4919696UL     // int32 sniff flag
#define TOPO_OFF 4919712UL     // bf16[50000][128] topo_pre
#define WS_NEED  18403840UL

#define RS8 0.35355339059327373f

#define MFMA(a,b,c) __builtin_amdgcn_mfma_f32_16x16x32_bf16((a),(b),(c),0,0,0)

__device__ inline f32x4 splat4(float v){ f32x4 r; r[0]=v; r[1]=v; r[2]=v; r[3]=v; return r; }
__device__ inline float scrub(float v){ return (v==v && v<1e30f && v>-1e30f) ? v : 0.f; }

// ---------------- dtype sniff for generate_mask (1 block) ----------------
__global__ void k_sniff(const void* gm_raw, char* ws) {
  __shared__ int big;
  if (threadIdx.x == 0) big = 0;
  __syncthreads();
  const unsigned* gw = (const unsigned*)gm_raw;
  for (int i = threadIdx.x; i < 12500; i += 256)
    if (gw[i] > 1u) big = 1;
  __syncthreads();
  if (threadIdx.x == 0) *(int*)(ws + FLAG_OFF) = big;
}

// ---- prep (merged): T, M1T/M2T, gm canon, PW, W2T', AAW, SCATTER ----
// blocks: [0,100) T, [100,116) transposes, [116,166) gm, [166,1190) PW,
// [1190,1318) W2T, [1318,1322) AAW, [1322,2104) scatter (raw gm via flag)
__global__ void k_prep(const float* atom_embed, const float* bond_embed,
                       const float* m0, const float* m1, const float* m2,
                       const float* g2, const float* gb2, const float* aa_embed,
                       const void* gm_raw, const int* __restrict__ bonds,
                       const int* __restrict__ A, char* ws) {
  int b = blockIdx.x, t = threadIdx.x;
  if (b < 100) {                       // T[a*5+bond][c] = relu(ae + be), f32
    float ae = atom_embed[b*128 + t];
    float* T = (float*)(ws + T_OFF);
    for (int bo = 0; bo < 5; ++bo) {
      float v = ae + bond_embed[bo*128 + t];
      T[(b*5 + bo)*128 + t] = v > 0.f ? v : 0.f;
    }
  } else if (b < 116) {                // weight transposes f32 -> bf16 [n][k]
    int wb = b - 100;
    const float* src; __bf16* dst; int r0;
    if (wb < 8) { src = m1; dst = (__bf16*)(ws + M1T_OFF); r0 = wb*16; }
    else        { src = m2; dst = (__bf16*)(ws + M2T_OFF); r0 = (wb-8)*16; }
    for (int rr = 0; rr < 16; ++rr) {
      int r = r0 + rr;
      dst[t*128 + r] = (__bf16)src[r*128 + t];
    }
  } else if (b < 166) {                // gm canon: 50 blocks x 1000 elems
    int anyBig = *(const int*)(ws + FLAG_OFF);
    int base = (b - 116) * 1000;
    unsigned char* gu = (unsigned char*)(ws + GM_OFF);
    if (anyBig) {
      const unsigned char* gb = (const unsigned char*)gm_raw;
      for (int i = t; i < 1000; i += 128) gu[base+i] = gb[base+i] ? 1 : 0;
    } else {
      const int* gi = (const int*)gm_raw;
      for (int i = t; i < 1000; i += 128) gu[base+i] = gi[base+i] ? 1 : 0;
    }
  } else if (b < 1190) {               // PW[p][t] = sum_j s(p,j)*W0[j][t], bf16
    int p = b - 166;
    __shared__ float s[128];
    int c = t & 63;
    float invf = exp2f((float)c * -0.20762050593046012f);  // 10000^(-c/64)
    float ang = (float)p * invf;
    s[t] = (t < 64) ? __sinf(ang) : __cosf(ang);
    __syncthreads();
    float acc = 0.f;
    #pragma unroll 4
    for (int j = 0; j < 128; ++j) acc += s[j] * m0[j*128 + t];
    ((__bf16*)(ws + PW_OFF))[p*128 + t] = (__bf16)acc;
  } else if (b < 1318) {               // W2T[c][r] = rs8 * sum_j W2[r][j]*W0[128+j][c]
    int r = b - 1190;
    float acc = 0.f;
    #pragma unroll 4
    for (int j = 0; j < 128; ++j) acc += g2[r*128 + j] * m0[(128+j)*128 + t];
    ((__bf16*)(ws + W2T_OFF))[t*128 + r] = (__bf16)(acc * RS8);
  } else if (b < 1322) {               // AAW[sf][t], sf = sel + 2*f
    int sf = b - 1318, sel = sf & 1, f = sf >> 1;
    float acc = 0.f;
    #pragma unroll 4
    for (int j = 0; j < 128; ++j) acc += aa_embed[sel*128 + j] * m0[(256+j)*128 + t];
    if (f) {
      float cacc = 0.f;
      #pragma unroll 4
      for (int j = 0; j < 128; ++j) cacc += gb2[j] * m0[(128+j)*128 + t];
      acc += 8.0f * RS8 * cacc;
    }
    ((float*)(ws + AAW_OFF))[sf*128 + t] = acc;
  } else {                             // SCATTER: 8 edges/thread, raw gm reads
    int anyBig = *(const int*)(ws + FLAG_OFF);
    const unsigned char* g8 = (const unsigned char*)gm_raw;
    const int* g32 = (const int*)gm_raw;
    long base = ((long)(b - 1322)*128 + t)*8;
    #pragma unroll 2
    for (int h = 0; h < 2; ++h) {
      long e4 = base + h*4;
      if (e4 >= NEDGE) break;
      const int4* bp = (const int4*)(bonds + e4*3);
      int4 w0 = bp[0], w1 = bp[1], w2 = bp[2];
      int srcs[4] = {w0.x, w0.w, w1.z, w2.y};
      int dsts[4] = {w0.y, w1.x, w1.w, w2.z};
      int bts[4]  = {w0.z, w1.y, w2.x, w2.w};
      #pragma unroll
      for (int i = 0; i < 4; ++i) {
        int sm_ = srcs[i] >> 3, dm = dsts[i] >> 3;
        int bad = anyBig ? ((int)g8[sm_] | (int)g8[dm]) : (g32[sm_] | g32[dm]);
        if (bad) continue;
        int slot = atomicAdd((int*)(ws + MCNT_OFF) + dm, 1);
        if (slot >= 0 && slot < CAP)
          ((unsigned short*)(ws + REC_OFF))[dm*CAP + slot] =
            (unsigned short)((A[srcs[i]]*5 + bts[i])*8 + (dsts[i] & 7));
      }
    }
  }
}

// ------- prep2: EW1 = emb@W1+b1, TW1 = T@W1 (in place over T) -------
__global__ void k_prep2(const float* atom_embed, const float* g1, const float* gb1,
                        char* ws) {
  int b = blockIdx.x, t = threadIdx.x;
  float s0 = 0.f, s1 = 0.f, s2 = 0.f, s3 = 0.f;
  const float* row = (b < 100) ? (atom_embed + b*128) : ((float*)(ws + T_OFF) + (b-100)*128);
  #pragma unroll 4
  for (int k = 0; k < 128; k += 4) {
    s0 += row[k+0] * g1[(k+0)*128 + t];
    s1 += row[k+1] * g1[(k+1)*128 + t];
    s2 += row[k+2] * g1[(k+2)*128 + t];
    s3 += row[k+3] * g1[(k+3)*128 + t];
  }
  float s = (s0 + s1) + (s2 + s3);
  if (b < 100) {
    ((float*)(ws + EW1_OFF))[b*128 + t] = s + gb1[t];
  } else {
    __syncthreads();
    ((float*)(ws + T_OFF))[(b-100)*128 + t] = s;
  }
}

// ---- gather5: wave-per-mol, zero LDS, 4 loads in flight (2 pair-loads/iter) ----
__launch_bounds__(256, 6)
__global__ void k_gather5(char* ws, const int* __restrict__ A) {
  const int tid = threadIdx.x;
  const int lane = tid & 63, wid = tid >> 6;
  const int mol = blockIdx.x*4 + wid;
  const int a_l = lane >> 3, q8 = lane & 7;
  const unsigned char* gm = (const unsigned char*)(ws + GM_OFF);

  f32x4 a0 = splat4(0.f), a1 = splat4(0.f), a2 = splat4(0.f), a3 = splat4(0.f);
  f32x4 b0 = splat4(0.f), b1 = splat4(0.f), b2 = splat4(0.f), b3 = splat4(0.f);
  if (!gm[mol]) {
    const int* cnt = (const int*)(ws + MCNT_OFF);
    const unsigned* rec32 = (const unsigned*)(ws + REC_OFF);
    const unsigned short* rec16 = (const unsigned short*)(ws + REC_OFF);
    const float* EW1 = (const float*)(ws + EW1_OFF);
    const float* TW1 = (const float*)(ws + T_OFF);
    int n = cnt[mol];
    if (n > CAP) n = CAP;
    if (n < 0) n = 0;
    int aT = A[mol*8 + a_l];
    const f32x4* ep = (const f32x4*)(EW1 + aT*128 + q8*16);
    a0 = ep[0]; a1 = ep[1]; a2 = ep[2]; a3 = ep[3];
    const int base32 = mol*(CAP/2);
    int i = 0;
    for (; i + 4 <= n; i += 4) {       // 4 independent TW1-row loads in flight
      unsigned pr0 = rec32[base32 + (i >> 1)];
      unsigned pr1 = rec32[base32 + (i >> 1) + 1];
      int rv0 = pr0 & 0xFFFF, rv1 = pr0 >> 16;
      int rv2 = pr1 & 0xFFFF, rv3 = pr1 >> 16;
      int p0 = rv0 >> 3, p1 = rv1 >> 3, p2 = rv2 >> 3, p3 = rv3 >> 3;
      if (p0 < 500 && (rv0 & 7) == a_l) {
        const f32x4* tp = (const f32x4*)(TW1 + p0*128 + q8*16);
        a0 += tp[0]; a1 += tp[1]; a2 += tp[2]; a3 += tp[3];
      }
      if (p1 < 500 && (rv1 & 7) == a_l) {
        const f32x4* tp = (const f32x4*)(TW1 + p1*128 + q8*16);
        b0 += tp[0]; b1 += tp[1]; b2 += tp[2]; b3 += tp[3];
      }
      if (p2 < 500 && (rv2 & 7) == a_l) {
        const f32x4* tp = (const f32x4*)(TW1 + p2*128 + q8*16);
        a0 += tp[0]; a1 += tp[1]; a2 += tp[2]; a3 += tp[3];
      }
      if (p3 < 500 && (rv3 & 7) == a_l) {
        const f32x4* tp = (const f32x4*)(TW1 + p3*128 + q8*16);
        b0 += tp[0]; b1 += tp[1]; b2 += tp[2]; b3 += tp[3];
      }
    }
    for (; i < n; ++i) {               // tail <= 3
      int rv = rec16[mol*CAP + i];
      int p = rv >> 3;
      if (p < 500 && (rv & 7) == a_l) {
        const f32x4* tp = (const f32x4*)(TW1 + p*128 + q8*16);
        b0 += tp[0]; b1 += tp[1]; b2 += tp[2]; b3 += tp[3];
      }
    }
  }
  // combine chains, relu, cross-atom reduce (lane bits 3..5)
  #pragma unroll
  for (int k = 0; k < 4; ++k) {
    float x0 = fmaxf(a0[k] + b0[k], 0.f), x1 = fmaxf(a1[k] + b1[k], 0.f);
    float x2 = fmaxf(a2[k] + b2[k], 0.f), x3 = fmaxf(a3[k] + b3[k], 0.f);
    x0 += __shfl_xor(x0, 8);  x1 += __shfl_xor(x1, 8);
    x2 += __shfl_xor(x2, 8);  x3 += __shfl_xor(x3, 8);
    x0 += __shfl_xor(x0, 16); x1 += __shfl_xor(x1, 16);
    x2 += __shfl_xor(x2, 16); x3 += __shfl_xor(x3, 16);
    x0 += __shfl_xor(x0, 32); x1 += __shfl_xor(x1, 32);
    x2 += __shfl_xor(x2, 32); x3 += __shfl_xor(x3, 32);
    a0[k] = x0; a1[k] = x1; a2[k] = x2; a3[k] = x3;
  }
  if (a_l == 0) {
    bf16x8 o0, o1;
    #pragma unroll
    for (int k = 0; k < 4; ++k) {
      o0[k] = (__bf16)a0[k]; o0[k+4] = (__bf16)a1[k];
      o1[k] = (__bf16)a2[k]; o1[k+4] = (__bf16)a3[k];
    }
    char* dst = ws + TOPO_OFF + (long)mol*256 + q8*32;
    *(bf16x8*)dst = o0;
    *(bf16x8*)(dst + 16) = o1;
  }
}

// ------------- GEMM core: 64x128 tile, 4 waves, K=128, single LDS panel -------------
__device__ inline void gemm4(const char* sm, int aoff, const __bf16* wt,
                             const float* bias, int lane, int wave, f32x4 acc[4][2]) {
  const int colA = wave*32 + (lane & 15);
  const int k0   = (lane >> 4) * 8;
  float bb0 = bias[colA], bb1 = bias[colA + 16];
  #pragma unroll
  for (int m = 0; m < 4; ++m) { acc[m][0] = splat4(bb0); acc[m][1] = splat4(bb1); }
  #pragma unroll
  for (int kb = 0; kb < 4; ++kb) {
    bf16x8 b0 = *(const bf16x8*)(wt + colA*128 + kb*32 + k0);
    bf16x8 b1 = *(const bf16x8*)(wt + (colA+16)*128 + kb*32 + k0);
    #pragma unroll
    for (int m = 0; m < 4; ++m) {
      int rA = m*16 + (lane & 15);
      int byte = aoff + rA*256 + (((kb*64) + k0*2) ^ ((rA & 7) << 4));
      bf16x8 a = *(const bf16x8*)(sm + byte);
      acc[m][0] = MFMA(a, b0, acc[m][0]);
      acc[m][1] = MFMA(a, b1, acc[m][1]);
    }
  }
}

__device__ inline void stor4(char* sm, int off, f32x4 acc[4][2],
                             int lane, int wave, bool do_relu) {
  #pragma unroll
  for (int m = 0; m < 4; ++m)
  #pragma unroll
  for (int nf = 0; nf < 2; ++nf)
  #pragma unroll
  for (int r = 0; r < 4; ++r) {
    float v = acc[m][nf][r];
    if (do_relu && v < 0.f) v = 0.f;
    int row = m*16 + (lane >> 4)*4 + r;
    int col = wave*32 + nf*16 + (lane & 15);
    int byte = off + row*256 + ((col*2) ^ ((row & 7) << 4));
    *(__bf16*)(sm + byte) = (__bf16)v;
  }
}

// ---- mlp3: stage topo_pre -> GEMM_T(K=128)+epilogue(PW/AAW) -> GEMM1 -> GEMM3 ----
__launch_bounds__(256)
__global__ void k_mlp3(char* ws, const int* __restrict__ pos_ids,
                       const int* __restrict__ is_aa, const float* cr,
                       const float* mb0, const float* mb1, const float* mb2,
                       float* __restrict__ out) {
  __shared__ __align__(16) char sm[32768];
  const int tid = threadIdx.x, lane = tid & 63, wave = tid >> 6;
  const int r0 = blockIdx.x * 64;
  const unsigned char* gm = (const unsigned char*)(ws + GM_OFF);
  const __bf16* topo_pre = (const __bf16*)(ws + TOPO_OFF);

  for (int i = 0; i < 4; ++i) {          // stage topo panel @0
    int idx = tid + i*256;
    int row = idx >> 4, c = idx & 15;
    int mol = r0 + row;
    bf16x8 v;
    #pragma unroll
    for (int j = 0; j < 8; ++j) v[j] = (__bf16)0.f;
    if (mol < NBLK) v = *(const bf16x8*)(topo_pre + (long)mol*128 + c*8);
    int byte = row*256 + ((c*16) ^ ((row & 7) << 4));
    *(bf16x8*)(sm + byte) = v;
  }
  if (tid < 64) {                        // per-row scalars @16384
    int mol = r0 + tid, packed = 0;
    if (mol < NBLK) {
      int g = gm[mol];
      int corrupt = g && (cr[mol] < 0.1f);
      int sel = corrupt ? 0 : is_aa[mol];
      packed = pos_ids[mol] | (sel << 12) | ((g ? 0 : 1) << 13);
    }
    *(int*)(sm + 16384 + tid*4) = packed;
  }
  __syncthreads();

  f32x4 acc[4][2];
  gemm4(sm, 0, (const __bf16*)(ws + W2T_OFF), mb0, lane, wave, acc);
  {
    const __bf16* PW = (const __bf16*)(ws + PW_OFF);
    const float* AAW = (const float*)(ws + AAW_OFF);
    #pragma unroll
    for (int m = 0; m < 4; ++m)
    #pragma unroll
    for (int r = 0; r < 4; ++r) {
      int row = m*16 + (lane >> 4)*4 + r;
      int packed = *(const int*)(sm + 16384 + row*4);
      int pid = packed & 0xFFF, sf = (packed >> 12) & 3;
      #pragma unroll
      for (int nf = 0; nf < 2; ++nf) {
        int col = wave*32 + nf*16 + (lane & 15);
        float v = acc[m][nf][r] + (float)PW[pid*128 + col] + AAW[sf*128 + col];
        acc[m][nf][r] = fmaxf(v, 0.f);
      }
    }
  }
  __syncthreads();
  stor4(sm, 0, acc, lane, wave, false);  // h1 over topo panel
  __syncthreads();

  gemm4(sm, 0, (const __bf16*)(ws + M1T_OFF), mb1, lane, wave, acc);
  stor4(sm, 16384, acc, lane, wave, true);
  __syncthreads();

  gemm4(sm, 16384, (const __bf16*)(ws + M2T_OFF), mb2, lane, wave, acc);
  #pragma unroll
  for (int m = 0; m < 4; ++m)
  #pragma unroll
  for (int nf = 0; nf < 2; ++nf)
  #pragma unroll
  for (int r = 0; r < 4; ++r) {
    int row = m*16 + (lane >> 4)*4 + r;
    int col = wave*32 + nf*16 + (lane & 15);
    int mol = r0 + row;
    if (mol < NBLK) out[(long)mol*128 + col] = scrub(acc[m][nf][r]);
  }
}

extern "C" void kernel_launch(void* const* d_in, const int* in_sizes, int n_in,
                              void* d_out, int out_size, void* d_ws, size_t ws_size,
                              hipStream_t stream) {
  if (ws_size < WS_NEED) return;   // diagnostic: absmax-fail instead of fault
  const int* A      = (const int*)d_in[0];
  const int* bonds  = (const int*)d_in[1];
  const void* gm    = d_in[3];
  const int* pos    = (const int*)d_in[4];
  const int* isaa   = (const int*)d_in[5];
  const float* cr   = (const float*)d_in[6];
  const float* atom_embed = (const float*)d_in[7];
  const float* bond_embed = (const float*)d_in[8];
  const float* aa_embed   = (const float*)d_in[9];
  const float* g1  = (const float*)d_in[10];
  const float* gb1 = (const float*)d_in[11];
  const float* g2  = (const float*)d_in[12];
  const float* gb2 = (const float*)d_in[13];
  const float* m0  = (const float*)d_in[14];
  const float* mb0 = (const float*)d_in[15];
  const float* m1  = (const float*)d_in[16];
  const float* mb1 = (const float*)d_in[17];
  const float* m2  = (const float*)d_in[18];
  const float* mb2 = (const float*)d_in[19];
  char* ws = (char*)d_ws;

  hipMemsetAsync(ws + MCNT_OFF, 0, (size_t)NBLK*4, stream);
  k_sniff  <<<1, 256, 0, stream>>>(gm, ws);
  k_prep   <<<2104, 128, 0, stream>>>(atom_embed, bond_embed, m0, m1, m2,
                                      g2, gb2, aa_embed, gm, bonds, A, ws);
  k_prep2  <<<600, 128, 0, stream>>>(atom_embed, g1, gb1, ws);   // EW1, TW1
  k_gather5<<<NBLK/4, 256, 0, stream>>>(ws, A);
  k_mlp3   <<<(NBLK + 63)/64, 256, 0, stream>>>(ws, pos, isaa, cr,
                                                mb0, mb1, mb2, (float*)d_out);
}